// Round 1
// baseline (13241.498 us; speedup 1.0000x reference)
//
#include <hip/hip_runtime.h>
#include <math.h>

#define BB 8
#define CC 512
#define TT 1024
#define SS 77
#define NHEADS 8
#define CHD 64
#define LL (SS + TT)   // 1101

// ---------------------------------------------------------------------------
// GroupNorm32: one block per (b, group). 16 channels x 1024 = 16384 floats.
// ---------------------------------------------------------------------------
__global__ __launch_bounds__(256) void groupnorm_kernel(
    const float* __restrict__ x, const float* __restrict__ scale,
    const float* __restrict__ bias, float* __restrict__ nrm) {
  int bg = blockIdx.x;          // b*32 + g
  int g = bg & 31;
  const float4* x4 = (const float4*)(x + (size_t)bg * 16384);
  float4* n4 = (float4*)(nrm + (size_t)bg * 16384);
  int tid = threadIdx.x;

  float s = 0.f, sq = 0.f;
  float4 vals[16];
#pragma unroll
  for (int i = 0; i < 16; ++i) {
    float4 v = x4[tid + 256 * i];
    vals[i] = v;
    s += v.x + v.y + v.z + v.w;
    sq += v.x * v.x + v.y * v.y + v.z * v.z + v.w * v.w;
  }
#pragma unroll
  for (int off = 32; off > 0; off >>= 1) {
    s += __shfl_down(s, off, 64);
    sq += __shfl_down(sq, off, 64);
  }
  __shared__ float red[8];
  int wave = tid >> 6;
  if ((tid & 63) == 0) { red[wave] = s; red[wave + 4] = sq; }
  __syncthreads();
  float ts = red[0] + red[1] + red[2] + red[3];
  float tq = red[4] + red[5] + red[6] + red[7];
  float mu = ts * (1.0f / 16384.0f);
  float var = tq * (1.0f / 16384.0f) - mu * mu;
  float rs = rsqrtf(var + 1e-5f);
#pragma unroll
  for (int i = 0; i < 16; ++i) {
    int c = g * 16 + i;                 // channel is uniform per i
    float sc = scale[c] * rs;
    float bi = bias[c] - mu * sc;
    float4 v = vals[i];
    v.x = v.x * sc + bi; v.y = v.y * sc + bi;
    v.z = v.z * sc + bi; v.w = v.w * sc + bi;
    n4[tid + 256 * i] = v;
  }
}

// ---------------------------------------------------------------------------
// Batched GEMM: C[b][o][t] = sum_c A[o][c] * Bm[b][c][t] + bias[o] (+res)
// K = 512 always. 64x64 tile, 256 threads, 4x4 micro-tile.
// ---------------------------------------------------------------------------
template <bool HAS_RES>
__global__ __launch_bounds__(256) void gemm_kernel(
    const float* __restrict__ A,    // [M][512]
    const float* __restrict__ Bm,   // [batch][512][N]
    const float* __restrict__ bias, // [M]
    const float* __restrict__ res,  // [batch][M][N] or null
    float* __restrict__ Cm,         // [batch][M][N]
    int M, int N) {
  const int K = 512;
  int b = blockIdx.z;
  int t0 = blockIdx.x * 64;
  int o0 = blockIdx.y * 64;
  const float* Bp = Bm + (size_t)b * K * N;
  float* Cp = Cm + (size_t)b * M * N;

  __shared__ float As[16][68];   // padded so As[kk][ty*4] is 16B-aligned
  __shared__ float Bs[16][64];

  int tid = threadIdx.x;
  int tx = tid & 15, ty = tid >> 4;
  float acc[4][4] = {};

  for (int k0 = 0; k0 < K; k0 += 16) {
    {
      int kk = tid & 15, ol = tid >> 4;
#pragma unroll
      for (int i = 0; i < 4; ++i) {
        int o = ol + 16 * i;
        As[kk][o] = A[(size_t)(o0 + o) * K + k0 + kk];
      }
    }
    {
      int tl = tid & 63, kk = tid >> 6;
#pragma unroll
      for (int i = 0; i < 4; ++i) {
        int kki = kk + 4 * i;
        int t = t0 + tl;
        Bs[kki][tl] = (t < N) ? Bp[(size_t)(k0 + kki) * N + t] : 0.f;
      }
    }
    __syncthreads();
#pragma unroll
    for (int kk = 0; kk < 16; ++kk) {
      float a_[4], b_[4];
#pragma unroll
      for (int i = 0; i < 4; ++i) a_[i] = As[kk][ty * 4 + i];
#pragma unroll
      for (int j = 0; j < 4; ++j) b_[j] = Bs[kk][tx * 4 + j];
#pragma unroll
      for (int i = 0; i < 4; ++i)
#pragma unroll
        for (int j = 0; j < 4; ++j) acc[i][j] += a_[i] * b_[j];
    }
    __syncthreads();
  }

#pragma unroll
  for (int i = 0; i < 4; ++i) {
    int o = o0 + ty * 4 + i;
    float bi = bias[o];
#pragma unroll
    for (int j = 0; j < 4; ++j) {
      int t = t0 + tx * 4 + j;
      if (t < N) {
        float v = acc[i][j] + bi;
        if (HAS_RES) v += res[(size_t)b * M * N + (size_t)o * N + t];
        Cp[(size_t)o * N + t] = v;
      }
    }
  }
}

// ---------------------------------------------------------------------------
// Attention: flash-style, one thread owns one query row (t).
// Block = 256 threads -> 256 rows; grid = (64 heads, 4 tiles).
// q row held in registers; K/V tiles (64ch x 32s) staged in LDS.
// Mask quirk: mask row = (b*HEADS+h) % B == h  (B==HEADS==8).
// ---------------------------------------------------------------------------
__global__ __launch_bounds__(256, 1) void attn_kernel(
    const float* __restrict__ qkv,   // [B][1536][T]
    const float* __restrict__ ekv,   // [B][1024][S]
    const int* __restrict__ mask,    // [B][S], 0/1
    float* __restrict__ attnout) {   // [B][512][T]
  int bh = blockIdx.x;               // 0..63
  int b = bh >> 3, h = bh & 7;
  int t = blockIdx.y * 256 + threadIdx.x;
  int tid = threadIdx.x;

  const float* qbase = qkv + ((size_t)b * 1536 + h * 192) * TT;
  const float* kbase = qbase + (size_t)64 * TT;
  const float* vbase = qbase + (size_t)128 * TT;
  const float* ekbase = ekv + ((size_t)b * 1024 + h * 128) * SS;
  const float* evbase = ekbase + (size_t)64 * SS;
  const int mrow = h;

  __shared__ float ks[64 * 32];
  __shared__ float vs[64 * 32];

  float q[64];
#pragma unroll
  for (int c = 0; c < 64; ++c) q[c] = qbase[(size_t)c * TT + t];

  float O[64];
#pragma unroll
  for (int c = 0; c < 64; ++c) O[c] = 0.f;
  float m = -1e30f, l = 0.f;

  for (int s0 = 0; s0 < LL; s0 += 32) {
    // stage K/V tile: 64ch x 32s, 8 elements per thread, coalesced in s
#pragma unroll
    for (int i = 0; i < 8; ++i) {
      int idx = tid + 256 * i;
      int c = idx >> 5, ss = idx & 31;
      int s = s0 + ss;
      float kv = 0.f, vv = 0.f;
      if (s < SS) {
        kv = ekbase[c * SS + s];
        vv = evbase[c * SS + s];
      } else if (s < LL) {
        kv = kbase[(size_t)c * TT + (s - SS)];
        vv = vbase[(size_t)c * TT + (s - SS)];
      }
      ks[idx] = kv;
      vs[idx] = vv;
    }
    __syncthreads();

    // scores for this tile
    float p[32];
#pragma unroll
    for (int j = 0; j < 32; ++j) p[j] = 0.f;
    for (int c = 0; c < 64; ++c) {
      float qc = q[c];
#pragma unroll
      for (int j = 0; j < 32; ++j) p[j] += qc * ks[c * 32 + j];
    }

    float tmax = -1e30f;
#pragma unroll
    for (int j = 0; j < 32; ++j) {
      int s = s0 + j;
      float sc = p[j] * 0.125f;
      if (s < SS) sc += (mask[mrow * SS + s] != 0) ? 0.f : -10000.f;
      if (s >= LL) sc = -1e30f;
      p[j] = sc;
      tmax = fmaxf(tmax, sc);
    }
    float newm = fmaxf(m, tmax);
    float alpha = __expf(m - newm);
    l *= alpha;
#pragma unroll
    for (int j = 0; j < 32; ++j) {
      float e = __expf(p[j] - newm);
      p[j] = e;
      l += e;
    }
    m = newm;

    for (int c = 0; c < 64; ++c) {
      float o = O[c] * alpha;
#pragma unroll
      for (int j = 0; j < 32; ++j) o += p[j] * vs[c * 32 + j];
      O[c] = o;
    }
    __syncthreads();
  }

  float inv = 1.0f / l;
  float* op = attnout + ((size_t)b * 512 + h * 64) * TT + t;
#pragma unroll
  for (int c = 0; c < 64; ++c) op[(size_t)c * TT] = O[c] * inv;
}

// ---------------------------------------------------------------------------
extern "C" void kernel_launch(void* const* d_in, const int* in_sizes, int n_in,
                              void* d_out, int out_size, void* d_ws, size_t ws_size,
                              hipStream_t stream) {
  const float* x       = (const float*)d_in[0];
  const float* enc     = (const float*)d_in[1];
  const int*   mask    = (const int*)d_in[2];
  const float* nscale  = (const float*)d_in[3];
  const float* nbias   = (const float*)d_in[4];
  const float* qkv_w   = (const float*)d_in[5];
  const float* qkv_b   = (const float*)d_in[6];
  const float* ekv_w   = (const float*)d_in[7];
  const float* ekv_b   = (const float*)d_in[8];
  const float* proj_w  = (const float*)d_in[9];
  const float* proj_b  = (const float*)d_in[10];
  float* out = (float*)d_out;

  char* ws = (char*)d_ws;
  float* nrm    = (float*)ws;                          // 16 MB; reused as attnout
  float* qkvbuf = (float*)(ws + (size_t)16 * 1024 * 1024);   // 48 MB
  float* ekvbuf = (float*)(ws + (size_t)64 * 1024 * 1024);   // ~2.5 MB

  // 1) GroupNorm32 + affine
  groupnorm_kernel<<<dim3(BB * 32), dim3(256), 0, stream>>>(x, nscale, nbias, nrm);

  // 2) qkv = qkv_w @ nrm + qkv_b      : [8][1536][1024]
  gemm_kernel<false><<<dim3(16, 24, BB), dim3(256), 0, stream>>>(
      qkv_w, nrm, qkv_b, nullptr, qkvbuf, 1536, 1024);

  // 3) ekv = ekv_w @ encoder_out + ekv_b : [8][1024][77]
  gemm_kernel<false><<<dim3(2, 16, BB), dim3(256), 0, stream>>>(
      ekv_w, enc, ekv_b, nullptr, ekvbuf, 1024, 77);

  // 4) attention -> attnout (reuses nrm buffer) : [8][512][1024]
  attn_kernel<<<dim3(64, 4), dim3(256), 0, stream>>>(qkvbuf, ekvbuf, mask, nrm);

  // 5) out = x + proj_w @ attnout + proj_b
  gemm_kernel<true><<<dim3(16, 8, BB), dim3(256), 0, stream>>>(
      proj_w, nrm, proj_b, x, out, 512, 1024);
}

// Round 2
// 555.196 us; speedup vs baseline: 23.8501x; 23.8501x over previous
//
#include <hip/hip_runtime.h>
#include <math.h>

#define BB 8
#define CC 512
#define TT 1024
#define SS 77
#define NHEADS 8
#define CHD 64
#define LL (SS + TT)   // 1101

typedef short v8s __attribute__((ext_vector_type(8)));
typedef float v4f __attribute__((ext_vector_type(4)));

__device__ __forceinline__ unsigned short f2bf(float f) {
  unsigned u = __float_as_uint(f);
  u = (u + 0x7fffu + ((u >> 16) & 1u)) >> 16;
  return (unsigned short)u;
}

// ---------------------------------------------------------------------------
// GroupNorm32: one block per (b, group). 16 channels x 1024 = 16384 floats.
// ---------------------------------------------------------------------------
__global__ __launch_bounds__(256) void groupnorm_kernel(
    const float* __restrict__ x, const float* __restrict__ scale,
    const float* __restrict__ bias, float* __restrict__ nrm) {
  int bg = blockIdx.x;          // b*32 + g
  int g = bg & 31;
  const float4* x4 = (const float4*)(x + (size_t)bg * 16384);
  float4* n4 = (float4*)(nrm + (size_t)bg * 16384);
  int tid = threadIdx.x;

  float s = 0.f, sq = 0.f;
  float4 vals[16];
#pragma unroll
  for (int i = 0; i < 16; ++i) {
    float4 v = x4[tid + 256 * i];
    vals[i] = v;
    s += v.x + v.y + v.z + v.w;
    sq += v.x * v.x + v.y * v.y + v.z * v.z + v.w * v.w;
  }
#pragma unroll
  for (int off = 32; off > 0; off >>= 1) {
    s += __shfl_down(s, off, 64);
    sq += __shfl_down(sq, off, 64);
  }
  __shared__ float red[8];
  int wave = tid >> 6;
  if ((tid & 63) == 0) { red[wave] = s; red[wave + 4] = sq; }
  __syncthreads();
  float ts = red[0] + red[1] + red[2] + red[3];
  float tq = red[4] + red[5] + red[6] + red[7];
  float mu = ts * (1.0f / 16384.0f);
  float var = tq * (1.0f / 16384.0f) - mu * mu;
  float rs = rsqrtf(var + 1e-5f);
#pragma unroll
  for (int i = 0; i < 16; ++i) {
    int c = g * 16 + i;                 // channel is uniform per i
    float sc = scale[c] * rs;
    float bi = bias[c] - mu * sc;
    float4 v = vals[i];
    v.x = v.x * sc + bi; v.y = v.y * sc + bi;
    v.z = v.z * sc + bi; v.w = v.w * sc + bi;
    n4[tid + 256 * i] = v;
  }
}

// ---------------------------------------------------------------------------
// Batched GEMM: C[b][o][t] = sum_c A[o][c] * Bm[b][c][t] + bias[o] (+res)
// K = 512 always. 64x64 tile, 256 threads, 4x4 micro-tile. (fp32 vector)
// ---------------------------------------------------------------------------
template <bool HAS_RES>
__global__ __launch_bounds__(256) void gemm_kernel(
    const float* __restrict__ A,    // [M][512]
    const float* __restrict__ Bm,   // [batch][512][N]
    const float* __restrict__ bias, // [M]
    const float* __restrict__ res,  // [batch][M][N] or null
    float* __restrict__ Cm,         // [batch][M][N]
    int M, int N) {
  const int K = 512;
  int b = blockIdx.z;
  int t0 = blockIdx.x * 64;
  int o0 = blockIdx.y * 64;
  const float* Bp = Bm + (size_t)b * K * N;
  float* Cp = Cm + (size_t)b * M * N;

  __shared__ float As[16][68];
  __shared__ float Bs[16][64];

  int tid = threadIdx.x;
  int tx = tid & 15, ty = tid >> 4;
  float acc[4][4] = {};

  for (int k0 = 0; k0 < K; k0 += 16) {
    {
      int kk = tid & 15, ol = tid >> 4;
#pragma unroll
      for (int i = 0; i < 4; ++i) {
        int o = ol + 16 * i;
        As[kk][o] = A[(size_t)(o0 + o) * K + k0 + kk];
      }
    }
    {
      int tl = tid & 63, kk = tid >> 6;
#pragma unroll
      for (int i = 0; i < 4; ++i) {
        int kki = kk + 4 * i;
        int t = t0 + tl;
        Bs[kki][tl] = (t < N) ? Bp[(size_t)(k0 + kki) * N + t] : 0.f;
      }
    }
    __syncthreads();
#pragma unroll
    for (int kk = 0; kk < 16; ++kk) {
      float a_[4], b_[4];
#pragma unroll
      for (int i = 0; i < 4; ++i) a_[i] = As[kk][ty * 4 + i];
#pragma unroll
      for (int j = 0; j < 4; ++j) b_[j] = Bs[kk][tx * 4 + j];
#pragma unroll
      for (int i = 0; i < 4; ++i)
#pragma unroll
        for (int j = 0; j < 4; ++j) acc[i][j] += a_[i] * b_[j];
    }
    __syncthreads();
  }

#pragma unroll
  for (int i = 0; i < 4; ++i) {
    int o = o0 + ty * 4 + i;
    float bi = bias[o];
#pragma unroll
    for (int j = 0; j < 4; ++j) {
      int t = t0 + tx * 4 + j;
      if (t < N) {
        float v = acc[i][j] + bi;
        if (HAS_RES) v += res[(size_t)b * M * N + (size_t)o * N + t];
        Cp[(size_t)o * N + t] = v;
      }
    }
  }
}

// ---------------------------------------------------------------------------
// MFMA flash attention (bf16 in, fp32 accumulate).
// Block = 256 thr = 4 waves. Block covers one (b,h) and 64 q-rows (t).
// Each wave owns a 16-row m-tile. s-chunks of 32 (2 n-tiles, 1 PV k-step).
// grid = (16 t-tiles, 64 bh).
//
// Layouts (16x16x32 bf16 MFMA, m89/m120-verified):
//   A-frag:  A[m = lane&15][k = quad*8 + j]  (8 bf16 contiguous in k)
//   B-frag:  B[k = quad*8 + j][n = lane&15]
//   C/D:     col = lane&15, row = quad*4 + reg
// LDS strides chosen so every b128 frag read is 16B-aligned, <=2-way bank.
// ---------------------------------------------------------------------------
#define QS_STRIDE 72   // [64 t][72]  bf16, rows 144B (16B-aligned)
#define KT_STRIDE 72   // [32 s][72]  bf16 (K transposed: row=s, col=ch)
#define VS_STRIDE 56   // [64 c][56]  bf16 (row=c, col=s), rows 112B
#define PS_STRIDE 56   // per-wave [16 t][56] bf16
#define OT_STRIDE 69   // [64 c][69]  fp32 epilogue transpose (aliases front)

#define OFF_Q 0
#define OFF_K 9216
#define OFF_V 13824
#define OFF_P 20992
#define OFF_M 28160
#define SMEM_BYTES 28480

__global__ __launch_bounds__(256) void attn_kernel(
    const float* __restrict__ qkv,   // [B][1536][T]
    const float* __restrict__ ekv,   // [B][1024][S]
    const int* __restrict__ mask,    // [B][S], 0/1
    float* __restrict__ attnout) {   // [B][512][T]
  __shared__ __align__(16) unsigned char smem[SMEM_BYTES];
  unsigned short* Qs = (unsigned short*)(smem + OFF_Q);
  unsigned short* Kt = (unsigned short*)(smem + OFF_K);
  unsigned short* Vs = (unsigned short*)(smem + OFF_V);
  unsigned short* Ps = (unsigned short*)(smem + OFF_P);
  float* AM = (float*)(smem + OFF_M);
  float* Ot = (float*)(smem + OFF_Q);   // aliases Q/K/V region (dead at epilogue)

  int bh = blockIdx.y;               // 0..63
  int b = bh >> 3, h = bh & 7;
  int t0 = blockIdx.x * 64;
  int tid = threadIdx.x;
  int lane = tid & 63;
  int lan15 = lane & 15;
  int quad = lane >> 4;
  int w = tid >> 6;

  const float* qbase = qkv + ((size_t)b * 1536 + h * 192) * TT;
  const float* kbase = qbase + (size_t)64 * TT;
  const float* vbase = qbase + (size_t)128 * TT;
  const float* ekbase = ekv + ((size_t)b * 1024 + h * 128) * SS;
  const float* evbase = ekbase + (size_t)64 * SS;

  // ---- stage Q tile [64 t][64 ch] (transposed from global) + mask row ----
#pragma unroll
  for (int i = 0; i < 16; ++i) {
    int idx = tid + 256 * i;            // 4096 elems
    int tl = idx & 63, ch = idx >> 6;   // coalesced read along t
    Qs[tl * QS_STRIDE + ch] = f2bf(qbase[(size_t)ch * TT + t0 + tl]);
  }
  if (tid < SS) AM[tid] = (mask[h * SS + tid] != 0) ? 0.f : -10000.f;

  // ---- per-wave state ----
  v4f Oacc[4];
#pragma unroll
  for (int nc = 0; nc < 4; ++nc) Oacc[nc] = (v4f){0.f, 0.f, 0.f, 0.f};
  float mrow[4] = {-1e30f, -1e30f, -1e30f, -1e30f};
  float lrow[4] = {0.f, 0.f, 0.f, 0.f};

  const int aq_off = (w * 16 + lan15) * QS_STRIDE + quad * 8;
  const int ap_off = lan15 * PS_STRIDE + quad * 8;
  unsigned short* Psw = Ps + w * 16 * PS_STRIDE;

  for (int s0 = 0; s0 < LL; s0 += 32) {
    __syncthreads();   // protect K/V LDS from previous chunk's readers
    // ---- stage K (transposed) and V tiles, fp32 -> bf16 ----
#pragma unroll
    for (int i = 0; i < 8; ++i) {
      int idx = tid + 256 * i;          // 2048 elems
      int srow = idx & 31, ch = idx >> 5;
      int s = s0 + srow;
      float kv = 0.f, vv = 0.f;
      if (s < SS) {
        kv = ekbase[ch * SS + s];
        vv = evbase[ch * SS + s];
      } else if (s < LL) {
        kv = kbase[(size_t)ch * TT + (s - SS)];
        vv = vbase[(size_t)ch * TT + (s - SS)];
      }
      Kt[srow * KT_STRIDE + ch] = f2bf(kv);
      Vs[ch * VS_STRIDE + srow] = f2bf(vv);
    }
    __syncthreads();

    // ---- QK^T: S-tile [16 t][32 s] per wave ----
    v8s aq0 = *(const v8s*)&Qs[aq_off];
    v8s aq1 = *(const v8s*)&Qs[aq_off + 32];
    v4f Sacc[2];
#pragma unroll
    for (int nt = 0; nt < 2; ++nt) {
      int brow = (nt * 16 + lan15) * KT_STRIDE + quad * 8;
      v8s bk0 = *(const v8s*)&Kt[brow];
      v8s bk1 = *(const v8s*)&Kt[brow + 32];
      v4f z = (v4f){0.f, 0.f, 0.f, 0.f};
      z = __builtin_amdgcn_mfma_f32_16x16x32_bf16(aq0, bk0, z, 0, 0, 0);
      z = __builtin_amdgcn_mfma_f32_16x16x32_bf16(aq1, bk1, z, 0, 0, 0);
      Sacc[nt] = z;
    }

    // ---- online softmax (rows live in (quad,reg); cols in lan15) ----
    float sc[2][4];
#pragma unroll
    for (int nt = 0; nt < 2; ++nt) {
      int s = s0 + nt * 16 + lan15;
      float add = (s < SS) ? AM[s] : ((s < LL) ? 0.f : -1e30f);
#pragma unroll
      for (int r = 0; r < 4; ++r) sc[nt][r] = Sacc[nt][r] * 0.125f + add;
    }
    float nm[4], alpha[4];
#pragma unroll
    for (int r = 0; r < 4; ++r) {
      float v = fmaxf(sc[0][r], sc[1][r]);
#pragma unroll
      for (int m2 = 1; m2 < 16; m2 <<= 1) v = fmaxf(v, __shfl_xor(v, m2, 64));
      nm[r] = fmaxf(mrow[r], v);
      alpha[r] = __expf(mrow[r] - nm[r]);
      mrow[r] = nm[r];
    }
    float psum[4];
#pragma unroll
    for (int r = 0; r < 4; ++r) {
      sc[0][r] = __expf(sc[0][r] - nm[r]);
      sc[1][r] = __expf(sc[1][r] - nm[r]);
      float v = sc[0][r] + sc[1][r];
#pragma unroll
      for (int m2 = 1; m2 < 16; m2 <<= 1) v += __shfl_xor(v, m2, 64);
      psum[r] = v;
      lrow[r] = lrow[r] * alpha[r] + psum[r];
#pragma unroll
      for (int nc = 0; nc < 4; ++nc) Oacc[nc][r] *= alpha[r];
    }
    // write P (bf16) into per-wave LDS tile in A-operand-friendly layout
#pragma unroll
    for (int nt = 0; nt < 2; ++nt)
#pragma unroll
      for (int r = 0; r < 4; ++r)
        Psw[(quad * 4 + r) * PS_STRIDE + nt * 16 + lan15] = f2bf(sc[nt][r]);
    __syncthreads();

    // ---- PV: O[16 t][64 c] += P[16 t][32 s] * V^T[32 s][64 c] ----
    v8s ap = *(const v8s*)&Psw[ap_off];
#pragma unroll
    for (int nc = 0; nc < 4; ++nc) {
      v8s bv = *(const v8s*)&Vs[(nc * 16 + lan15) * VS_STRIDE + quad * 8];
      Oacc[nc] = __builtin_amdgcn_mfma_f32_16x16x32_bf16(ap, bv, Oacc[nc], 0, 0, 0);
    }
  }

  // ---- epilogue: normalize, transpose through LDS, coalesced store ----
  float inv[4];
#pragma unroll
  for (int r = 0; r < 4; ++r) inv[r] = 1.0f / lrow[r];
  __syncthreads();   // everyone done with Q/K/V/P region before aliasing as Ot
#pragma unroll
  for (int nc = 0; nc < 4; ++nc)
#pragma unroll
    for (int r = 0; r < 4; ++r)
      Ot[(nc * 16 + lan15) * OT_STRIDE + w * 16 + quad * 4 + r] =
          Oacc[nc][r] * inv[r];
  __syncthreads();

  {
    int c = tid >> 2;
    int seg = (tid & 3) * 16;
    float* op = attnout + ((size_t)b * 512 + h * 64 + c) * TT + t0 + seg;
#pragma unroll
    for (int j = 0; j < 4; ++j) {
      float4 v;
      v.x = Ot[c * OT_STRIDE + seg + j * 4 + 0];
      v.y = Ot[c * OT_STRIDE + seg + j * 4 + 1];
      v.z = Ot[c * OT_STRIDE + seg + j * 4 + 2];
      v.w = Ot[c * OT_STRIDE + seg + j * 4 + 3];
      *(float4*)(op + j * 4) = v;
    }
  }
}

// ---------------------------------------------------------------------------
extern "C" void kernel_launch(void* const* d_in, const int* in_sizes, int n_in,
                              void* d_out, int out_size, void* d_ws, size_t ws_size,
                              hipStream_t stream) {
  const float* x       = (const float*)d_in[0];
  const float* enc     = (const float*)d_in[1];
  const int*   mask    = (const int*)d_in[2];
  const float* nscale  = (const float*)d_in[3];
  const float* nbias   = (const float*)d_in[4];
  const float* qkv_w   = (const float*)d_in[5];
  const float* qkv_b   = (const float*)d_in[6];
  const float* ekv_w   = (const float*)d_in[7];
  const float* ekv_b   = (const float*)d_in[8];
  const float* proj_w  = (const float*)d_in[9];
  const float* proj_b  = (const float*)d_in[10];
  float* out = (float*)d_out;

  char* ws = (char*)d_ws;
  float* nrm    = (float*)ws;                          // 16 MB; reused as attnout
  float* qkvbuf = (float*)(ws + (size_t)16 * 1024 * 1024);   // 48 MB
  float* ekvbuf = (float*)(ws + (size_t)64 * 1024 * 1024);   // ~2.5 MB

  // 1) GroupNorm32 + affine
  groupnorm_kernel<<<dim3(BB * 32), dim3(256), 0, stream>>>(x, nscale, nbias, nrm);

  // 2) qkv = qkv_w @ nrm + qkv_b      : [8][1536][1024]
  gemm_kernel<false><<<dim3(16, 24, BB), dim3(256), 0, stream>>>(
      qkv_w, nrm, qkv_b, nullptr, qkvbuf, 1536, 1024);

  // 3) ekv = ekv_w @ encoder_out + ekv_b : [8][1024][77]
  gemm_kernel<false><<<dim3(2, 16, BB), dim3(256), 0, stream>>>(
      ekv_w, enc, ekv_b, nullptr, ekvbuf, 1024, 77);

  // 4) MFMA flash attention -> attnout (reuses nrm buffer) : [8][512][1024]
  attn_kernel<<<dim3(16, 64), dim3(256), 0, stream>>>(qkvbuf, ekvbuf, mask, nrm);

  // 5) out = x + proj_w @ attnout + proj_b
  gemm_kernel<true><<<dim3(16, 8, BB), dim3(256), 0, stream>>>(
      proj_w, nrm, proj_b, x, out, 512, 1024);
}

// Round 3
// 300.589 us; speedup vs baseline: 44.0519x; 1.8470x over previous
//
#include <hip/hip_runtime.h>
#include <math.h>

#define BB 8
#define CC 512
#define TT 1024
#define SS 77
#define NHEADS 8
#define CHD 64
#define LL (SS + TT)   // 1101

typedef short v8s __attribute__((ext_vector_type(8)));
typedef float v4f __attribute__((ext_vector_type(4)));
typedef unsigned short u16x4 __attribute__((ext_vector_type(4)));
typedef unsigned short u16x8 __attribute__((ext_vector_type(8)));

__device__ __forceinline__ unsigned short f2bf(float f) {
  unsigned u = __float_as_uint(f);
  u = (u + 0x7fffu + ((u >> 16) & 1u)) >> 16;
  return (unsigned short)u;
}
__device__ __forceinline__ float bf2f(unsigned short u) {
  return __uint_as_float(((unsigned)u) << 16);
}

// async global->LDS, 16B per lane. LDS base must be wave-uniform.
__device__ __forceinline__ void gl_lds16(const void* g, void* l) {
  __builtin_amdgcn_global_load_lds(
      (const __attribute__((address_space(1))) void*)g,
      (__attribute__((address_space(3))) void*)l, 16, 0, 0);
}

// ---------------------------------------------------------------------------
// prep: fp32->bf16 weight conversion + encoder transpose (zero-padded to 128)
// ---------------------------------------------------------------------------
__global__ __launch_bounds__(256) void prep_kernel(
    const float* __restrict__ qkv_w, const float* __restrict__ ekv_w,
    const float* __restrict__ proj_w, const float* __restrict__ enc,
    unsigned short* __restrict__ qkv_wb, unsigned short* __restrict__ ekv_wb,
    unsigned short* __restrict__ proj_wb, unsigned short* __restrict__ encT) {
  int blk = blockIdx.x, tid = threadIdx.x;
  if (blk < 1536) {
    const float* src;
    unsigned short* dst;
    int idx;
    if (blk < 768)      { src = qkv_w;  dst = qkv_wb;  idx = blk * 256 + tid; }
    else if (blk < 1280){ src = ekv_w;  dst = ekv_wb;  idx = (blk - 768) * 256 + tid; }
    else                { src = proj_w; dst = proj_wb; idx = (blk - 1280) * 256 + tid; }
    float4 v = ((const float4*)src)[idx];
    u16x4 o; o.x = f2bf(v.x); o.y = f2bf(v.y); o.z = f2bf(v.z); o.w = f2bf(v.w);
    *(u16x4*)(dst + (size_t)idx * 4) = o;
  } else {
    int idx = (blk - 1536) * 256 + tid;          // 131072 total
    int b = idx >> 14, rem = idx & 16383;
    int s = rem >> 7, c = (rem & 127) * 4;
    u16x4 o; o.x = 0; o.y = 0; o.z = 0; o.w = 0;
    if (s < SS) {
      const float* p = enc + ((size_t)b * 512 + c) * SS + s;
      o.x = f2bf(p[0]); o.y = f2bf(p[SS]); o.z = f2bf(p[2 * SS]); o.w = f2bf(p[3 * SS]);
    }
    *(u16x4*)(encT + ((size_t)b * 128 + s) * 512 + c) = o;
  }
}

// ---------------------------------------------------------------------------
// GroupNorm32 -> transposed bf16 output nrmT[b][t][c].
// One block per (b,g): 16 channels x 1024 t. Raw x staged bf16 in LDS,
// stats in fp32, phase-2 reads LDS transposed and writes 32B rows.
// ---------------------------------------------------------------------------
__global__ __launch_bounds__(256) void gn_kernel(
    const float* __restrict__ x, const float* __restrict__ scale,
    const float* __restrict__ bias, unsigned short* __restrict__ nrmT) {
  int bg = blockIdx.x;          // b*32 + g
  int b = bg >> 5, g = bg & 31;
  __shared__ unsigned short Xs[16 * 1024];
  __shared__ float red[8];
  const float4* x4 = (const float4*)(x + (size_t)bg * 16384);
  int tid = threadIdx.x;

  float s = 0.f, sq = 0.f;
#pragma unroll
  for (int i = 0; i < 16; ++i) {
    int idx = tid + 256 * i;
    float4 v = x4[idx];
    s += v.x + v.y + v.z + v.w;
    sq += v.x * v.x + v.y * v.y + v.z * v.z + v.w * v.w;
    int c = idx >> 8, t4 = (idx & 255) * 4;
    u16x4 o; o.x = f2bf(v.x); o.y = f2bf(v.y); o.z = f2bf(v.z); o.w = f2bf(v.w);
    *(u16x4*)(Xs + c * 1024 + t4) = o;
  }
#pragma unroll
  for (int off = 32; off > 0; off >>= 1) {
    s += __shfl_down(s, off, 64);
    sq += __shfl_down(sq, off, 64);
  }
  int wave = tid >> 6;
  if ((tid & 63) == 0) { red[wave] = s; red[wave + 4] = sq; }
  __syncthreads();
  float ts = red[0] + red[1] + red[2] + red[3];
  float tq = red[4] + red[5] + red[6] + red[7];
  float mu = ts * (1.0f / 16384.0f);
  float var = tq * (1.0f / 16384.0f) - mu * mu;
  float rs = rsqrtf(var + 1e-5f);

  float scv[16], biv[16];
#pragma unroll
  for (int c = 0; c < 16; ++c) {
    float ss = scale[g * 16 + c] * rs;
    scv[c] = ss;
    biv[c] = bias[g * 16 + c] - mu * ss;
  }
#pragma unroll
  for (int j = 0; j < 4; ++j) {
    int t = tid + 256 * j;
    u16x8 o0, o1;
#pragma unroll
    for (int c = 0; c < 8; ++c)
      o0[c] = f2bf(bf2f(Xs[c * 1024 + t]) * scv[c] + biv[c]);
#pragma unroll
    for (int c = 8; c < 16; ++c)
      o1[c - 8] = f2bf(bf2f(Xs[c * 1024 + t]) * scv[c] + biv[c]);
    unsigned short* dst = nrmT + ((size_t)b * 1024 + t) * 512 + g * 16;
    *(u16x8*)dst = o0;
    *(u16x8*)(dst + 8) = o1;
  }
}

// ---------------------------------------------------------------------------
// MFMA GEMM (m97 structure): C[b][m][n] = A[m][k] * B[b][n][k]^T + bias.
// Both operands bf16, K-contiguous (K=512). 128x128 tile, BK=64, 4 waves.
// global_load_lds width=16 with XOR swizzle baked into global addresses so
// ds_read_b128 fragment reads are bank-conflict-free.
// MODE 0: bf16 out + bias.  MODE 1: + n<Nlim store predicate.
// MODE 2: fp32 out + bias + residual.
// ---------------------------------------------------------------------------
template <int MODE>
__global__ __launch_bounds__(256) void mfma_gemm(
    const unsigned short* __restrict__ A,   // [M][512] bf16
    const unsigned short* __restrict__ B,   // [batch][Brows][512] bf16
    const float* __restrict__ bias,         // [M]
    const float* __restrict__ res,          // fp32 (MODE 2)
    void* __restrict__ Cv,
    int Brows, int Cn, int Nlim, size_t Cbatch) {
  __shared__ __align__(16) unsigned short As[8192];  // [128][64] swizzled
  __shared__ __align__(16) unsigned short Bs[8192];

  int tid = threadIdx.x;
  int lane = tid & 63, w = tid >> 6;
  int lan15 = lane & 15, quad = lane >> 4;
  int wm = w >> 1, wn = w & 1;
  int m0 = blockIdx.y * 128, n0 = blockIdx.x * 128;
  int bz = blockIdx.z;

  // staging addresses: lane covers row (lane>>3), 16B-chunk (lane&7),
  // global chunk swizzled by row&7 (== lane>>3 within an 8-row group).
  int srow = lane >> 3;
  int schunk = (lane & 7) ^ srow;
  const char* Ag = (const char*)(A + (size_t)(m0 + w * 32 + srow) * 512) + schunk * 16;
  const char* Bg = (const char*)(B + ((size_t)bz * Brows + n0 + w * 32 + srow) * 512) + schunk * 16;
  char* Al = (char*)As + w * 4096;
  char* Bl = (char*)Bs + w * 4096;

  v4f acc[4][4] = {};

  for (int step = 0; step < 8; ++step) {
    __syncthreads();
    int kb = step * 128;   // 64 bf16 = 128 bytes
#pragma unroll
    for (int i = 0; i < 4; ++i)
      gl_lds16(Ag + kb + i * 8192, Al + i * 1024);
#pragma unroll
    for (int i = 0; i < 4; ++i)
      gl_lds16(Bg + kb + i * 8192, Bl + i * 1024);
    __syncthreads();

#pragma unroll
    for (int ksub = 0; ksub < 2; ++ksub) {
      int ch = ((ksub * 4 + quad) ^ (lan15 & 7)) * 16;
      v8s a[4], bf[4];
#pragma unroll
      for (int i = 0; i < 4; ++i) {
        int row = wm * 64 + i * 16 + lan15;
        a[i] = *(const v8s*)((const char*)As + row * 128 + ch);
      }
#pragma unroll
      for (int j = 0; j < 4; ++j) {
        int row = wn * 64 + j * 16 + lan15;
        bf[j] = *(const v8s*)((const char*)Bs + row * 128 + ch);
      }
#pragma unroll
      for (int i = 0; i < 4; ++i)
#pragma unroll
        for (int j = 0; j < 4; ++j)
          acc[i][j] = __builtin_amdgcn_mfma_f32_16x16x32_bf16(a[i], bf[j], acc[i][j], 0, 0, 0);
    }
  }

  // epilogue
#pragma unroll
  for (int i = 0; i < 4; ++i) {
    int ob = m0 + wm * 64 + i * 16 + quad * 4;
#pragma unroll
    for (int r = 0; r < 4; ++r) {
      int o = ob + r;
      float bi = bias[o];
#pragma unroll
      for (int j = 0; j < 4; ++j) {
        int n = n0 + wn * 64 + j * 16 + lan15;
        if (MODE == 1 && n >= Nlim) continue;
        if (MODE == 2) {
          float* C = (float*)Cv + bz * Cbatch;
          float v = acc[i][j][r] + bi + res[bz * Cbatch + (size_t)o * Cn + n];
          C[(size_t)o * Cn + n] = v;
        } else {
          unsigned short* C = (unsigned short*)Cv + bz * Cbatch;
          C[(size_t)o * Cn + n] = f2bf(acc[i][j][r] + bi);
        }
      }
    }
  }
}

// ---------------------------------------------------------------------------
// MFMA flash attention (bf16 in, fp32 accumulate), bf16 transposed output.
// Block = 4 waves, covers one (b,h) and 64 q-rows. s-chunks of 32.
// ---------------------------------------------------------------------------
#define QS_STRIDE 72
#define KT_STRIDE 72
#define VS_STRIDE 56
#define PS_STRIDE 56
#define OT_STRIDE 68   // fp32 [64 t][68]

#define OFF_Q 0
#define OFF_K 9216
#define OFF_V 13824
#define OFF_P 20992
#define OFF_M 28160
#define SMEM_BYTES 28480

__global__ __launch_bounds__(256) void attn_kernel(
    const unsigned short* __restrict__ qkv,   // [B][1536][T] bf16
    const unsigned short* __restrict__ ekv,   // [B][1024][S] bf16
    const int* __restrict__ mask,             // [B][S]
    unsigned short* __restrict__ attnT) {     // [B][T][512] bf16
  __shared__ __align__(16) unsigned char smem[SMEM_BYTES];
  unsigned short* Qs = (unsigned short*)(smem + OFF_Q);
  unsigned short* Kt = (unsigned short*)(smem + OFF_K);
  unsigned short* Vs = (unsigned short*)(smem + OFF_V);
  unsigned short* Ps = (unsigned short*)(smem + OFF_P);
  float* AM = (float*)(smem + OFF_M);
  float* Ot = (float*)(smem + OFF_Q);

  int bh = blockIdx.y;
  int b = bh >> 3, h = bh & 7;
  int t0 = blockIdx.x * 64;
  int tid = threadIdx.x;
  int lane = tid & 63;
  int lan15 = lane & 15;
  int quad = lane >> 4;
  int w = tid >> 6;

  const unsigned short* qbase = qkv + ((size_t)b * 1536 + h * 192) * TT;
  const unsigned short* kbase = qbase + (size_t)64 * TT;
  const unsigned short* vbase = qbase + (size_t)128 * TT;
  const unsigned short* ekbase = ekv + ((size_t)b * 1024 + h * 128) * SS;
  const unsigned short* evbase = ekbase + (size_t)64 * SS;

#pragma unroll
  for (int i = 0; i < 16; ++i) {
    int idx = tid + 256 * i;
    int tl = idx & 63, ch = idx >> 6;
    Qs[tl * QS_STRIDE + ch] = qbase[(size_t)ch * TT + t0 + tl];
  }
  if (tid < SS) AM[tid] = (mask[h * SS + tid] != 0) ? 0.f : -10000.f;

  v4f Oacc[4];
#pragma unroll
  for (int nc = 0; nc < 4; ++nc) Oacc[nc] = (v4f){0.f, 0.f, 0.f, 0.f};
  float mrow[4] = {-1e30f, -1e30f, -1e30f, -1e30f};
  float lrow[4] = {0.f, 0.f, 0.f, 0.f};

  const int aq_off = (w * 16 + lan15) * QS_STRIDE + quad * 8;
  const int ap_off = lan15 * PS_STRIDE + quad * 8;
  unsigned short* Psw = Ps + w * 16 * PS_STRIDE;

  for (int s0 = 0; s0 < LL; s0 += 32) {
    __syncthreads();
#pragma unroll
    for (int i = 0; i < 8; ++i) {
      int idx = tid + 256 * i;
      int srow = idx & 31, ch = idx >> 5;
      int s = s0 + srow;
      unsigned short kv = 0, vv = 0;
      if (s < SS) {
        kv = ekbase[ch * SS + s];
        vv = evbase[ch * SS + s];
      } else if (s < LL) {
        kv = kbase[(size_t)ch * TT + (s - SS)];
        vv = vbase[(size_t)ch * TT + (s - SS)];
      }
      Kt[srow * KT_STRIDE + ch] = kv;
      Vs[ch * VS_STRIDE + srow] = vv;
    }
    __syncthreads();

    v8s aq0 = *(const v8s*)&Qs[aq_off];
    v8s aq1 = *(const v8s*)&Qs[aq_off + 32];
    v4f Sacc[2];
#pragma unroll
    for (int nt = 0; nt < 2; ++nt) {
      int brow = (nt * 16 + lan15) * KT_STRIDE + quad * 8;
      v8s bk0 = *(const v8s*)&Kt[brow];
      v8s bk1 = *(const v8s*)&Kt[brow + 32];
      v4f z = (v4f){0.f, 0.f, 0.f, 0.f};
      z = __builtin_amdgcn_mfma_f32_16x16x32_bf16(aq0, bk0, z, 0, 0, 0);
      z = __builtin_amdgcn_mfma_f32_16x16x32_bf16(aq1, bk1, z, 0, 0, 0);
      Sacc[nt] = z;
    }

    float sc[2][4];
#pragma unroll
    for (int nt = 0; nt < 2; ++nt) {
      int s = s0 + nt * 16 + lan15;
      float add = (s < SS) ? AM[s] : ((s < LL) ? 0.f : -1e30f);
#pragma unroll
      for (int r = 0; r < 4; ++r) sc[nt][r] = Sacc[nt][r] * 0.125f + add;
    }
    float nm[4], alpha[4];
#pragma unroll
    for (int r = 0; r < 4; ++r) {
      float v = fmaxf(sc[0][r], sc[1][r]);
#pragma unroll
      for (int m2 = 1; m2 < 16; m2 <<= 1) v = fmaxf(v, __shfl_xor(v, m2, 64));
      nm[r] = fmaxf(mrow[r], v);
      alpha[r] = __expf(mrow[r] - nm[r]);
      mrow[r] = nm[r];
    }
#pragma unroll
    for (int r = 0; r < 4; ++r) {
      sc[0][r] = __expf(sc[0][r] - nm[r]);
      sc[1][r] = __expf(sc[1][r] - nm[r]);
      float v = sc[0][r] + sc[1][r];
#pragma unroll
      for (int m2 = 1; m2 < 16; m2 <<= 1) v += __shfl_xor(v, m2, 64);
      lrow[r] = lrow[r] * alpha[r] + v;
#pragma unroll
      for (int nc = 0; nc < 4; ++nc) Oacc[nc][r] *= alpha[r];
    }
#pragma unroll
    for (int nt = 0; nt < 2; ++nt)
#pragma unroll
      for (int r = 0; r < 4; ++r)
        Psw[(quad * 4 + r) * PS_STRIDE + nt * 16 + lan15] = f2bf(sc[nt][r]);
    __syncthreads();

    v8s ap = *(const v8s*)&Psw[ap_off];
#pragma unroll
    for (int nc = 0; nc < 4; ++nc) {
      v8s bv = *(const v8s*)&Vs[(nc * 16 + lan15) * VS_STRIDE + quad * 8];
      Oacc[nc] = __builtin_amdgcn_mfma_f32_16x16x32_bf16(ap, bv, Oacc[nc], 0, 0, 0);
    }
  }

  float inv[4];
#pragma unroll
  for (int r = 0; r < 4; ++r) inv[r] = 1.0f / lrow[r];
  __syncthreads();
#pragma unroll
  for (int nc = 0; nc < 4; ++nc)
#pragma unroll
    for (int r = 0; r < 4; ++r)
      Ot[(w * 16 + quad * 4 + r) * OT_STRIDE + nc * 16 + lan15] = Oacc[nc][r] * inv[r];
  __syncthreads();

  {
    int tl = tid >> 2;
    int seg = (tid & 3) * 16;
    u16x8 o0, o1;
#pragma unroll
    for (int k = 0; k < 8; ++k) o0[k] = f2bf(Ot[tl * OT_STRIDE + seg + k]);
#pragma unroll
    for (int k = 8; k < 16; ++k) o1[k - 8] = f2bf(Ot[tl * OT_STRIDE + seg + k]);
    unsigned short* op = attnT + ((size_t)b * 1024 + t0 + tl) * 512 + h * 64 + seg;
    *(u16x8*)op = o0;
    *(u16x8*)(op + 8) = o1;
  }
}

// ---------------------------------------------------------------------------
extern "C" void kernel_launch(void* const* d_in, const int* in_sizes, int n_in,
                              void* d_out, int out_size, void* d_ws, size_t ws_size,
                              hipStream_t stream) {
  const float* x       = (const float*)d_in[0];
  const float* enc     = (const float*)d_in[1];
  const int*   mask    = (const int*)d_in[2];
  const float* nscale  = (const float*)d_in[3];
  const float* nbias   = (const float*)d_in[4];
  const float* qkv_w   = (const float*)d_in[5];
  const float* qkv_b   = (const float*)d_in[6];
  const float* ekv_w   = (const float*)d_in[7];
  const float* ekv_b   = (const float*)d_in[8];
  const float* proj_w  = (const float*)d_in[9];
  const float* proj_b  = (const float*)d_in[10];
  float* out = (float*)d_out;

  char* ws = (char*)d_ws;
  unsigned short* qkvbuf = (unsigned short*)(ws);                    // 24 MB [8][1536][1024]
  unsigned short* nrmT   = (unsigned short*)(ws + 25165824);         // 8 MB  [8][1024][512]
  unsigned short* attnT  = (unsigned short*)(ws + 33554432);         // 8 MB  [8][1024][512]
  unsigned short* ekvbuf = (unsigned short*)(ws + 41943040);         // ~1.2 MB [8][1024][77]
  unsigned short* encT   = (unsigned short*)(ws + 44040192);         // 1 MB [8][128][512]
  unsigned short* qkv_wb = (unsigned short*)(ws + 45088768);         // 1.5 MB
  unsigned short* ekv_wb = (unsigned short*)(ws + 46661632);         // 1 MB
  unsigned short* proj_wb= (unsigned short*)(ws + 47710208);         // 0.5 MB

  // 1) weights->bf16, encoder transpose (independent of gn)
  prep_kernel<<<dim3(2048), dim3(256), 0, stream>>>(
      qkv_w, ekv_w, proj_w, enc, qkv_wb, ekv_wb, proj_wb, encT);

  // 2) GroupNorm32 -> nrmT bf16 [b][t][c]
  gn_kernel<<<dim3(BB * 32), dim3(256), 0, stream>>>(x, nscale, nbias, nrmT);

  // 3) qkv = qkv_w @ nrm : [8][1536][1024] bf16
  mfma_gemm<0><<<dim3(8, 12, BB), dim3(256), 0, stream>>>(
      qkv_wb, nrmT, qkv_b, nullptr, qkvbuf, 1024, 1024, 1024, (size_t)1536 * 1024);

  // 4) ekv = ekv_w @ enc : [8][1024][77] bf16
  mfma_gemm<1><<<dim3(1, 8, BB), dim3(256), 0, stream>>>(
      ekv_wb, encT, ekv_b, nullptr, ekvbuf, 128, 77, 77, (size_t)1024 * 77);

  // 5) attention -> attnT bf16 [8][1024][512]
  attn_kernel<<<dim3(16, 64), dim3(256), 0, stream>>>(qkvbuf, ekvbuf, mask, attnT);

  // 6) out = x + proj_w @ attn : fp32 [8][512][1024]
  mfma_gemm<2><<<dim3(8, 4, BB), dim3(256), 0, stream>>>(
      proj_wb, attnT, proj_b, x, out, 1024, 1024, 1024, (size_t)512 * 1024);
}

// Round 4
// 234.320 us; speedup vs baseline: 56.5104x; 1.2828x over previous
//
#include <hip/hip_runtime.h>
#include <math.h>

#define BB 8
#define CC 512
#define TT 1024
#define SS 77
#define NHEADS 8
#define CHD 64

typedef short v8s __attribute__((ext_vector_type(8)));
typedef float v4f __attribute__((ext_vector_type(4)));
typedef unsigned short u16x4 __attribute__((ext_vector_type(4)));
typedef unsigned short u16x8 __attribute__((ext_vector_type(8)));
typedef unsigned short u16;

__device__ __forceinline__ unsigned short f2bf(float f) {
  unsigned u = __float_as_uint(f);
  u = (u + 0x7fffu + ((u >> 16) & 1u)) >> 16;
  return (unsigned short)u;
}
__device__ __forceinline__ float bf2f(unsigned short u) {
  return __uint_as_float(((unsigned)u) << 16);
}

// async global->LDS, 16B per lane; LDS base must be wave-uniform.
__device__ __forceinline__ void gl_lds16(const void* g, void* l) {
  __builtin_amdgcn_global_load_lds(
      (const __attribute__((address_space(1))) void*)g,
      (__attribute__((address_space(3))) void*)l, 16, 0, 0);
}

// 16-lane butterfly reductions: xor1,xor2 via DPP quad_perm, xor4 via
// ds_swizzle, xor8 via DPP row_ror:8. Domain = contiguous 16-lane groups.
__device__ __forceinline__ float red16max(float v) {
  int i;
  i = __builtin_amdgcn_update_dpp(__float_as_int(v), __float_as_int(v), 0xB1, 0xF, 0xF, true);
  v = fmaxf(v, __int_as_float(i));
  i = __builtin_amdgcn_update_dpp(__float_as_int(v), __float_as_int(v), 0x4E, 0xF, 0xF, true);
  v = fmaxf(v, __int_as_float(i));
  i = __builtin_amdgcn_ds_swizzle(__float_as_int(v), 0x101F);
  v = fmaxf(v, __int_as_float(i));
  i = __builtin_amdgcn_update_dpp(__float_as_int(v), __float_as_int(v), 0x128, 0xF, 0xF, true);
  v = fmaxf(v, __int_as_float(i));
  return v;
}
__device__ __forceinline__ float red16sum(float v) {
  int i;
  i = __builtin_amdgcn_update_dpp(__float_as_int(v), __float_as_int(v), 0xB1, 0xF, 0xF, true);
  v += __int_as_float(i);
  i = __builtin_amdgcn_update_dpp(__float_as_int(v), __float_as_int(v), 0x4E, 0xF, 0xF, true);
  v += __int_as_float(i);
  i = __builtin_amdgcn_ds_swizzle(__float_as_int(v), 0x101F);
  v += __int_as_float(i);
  i = __builtin_amdgcn_update_dpp(__float_as_int(v), __float_as_int(v), 0x128, 0xF, 0xF, true);
  v += __int_as_float(i);
  return v;
}

// ---------------------------------------------------------------------------
// prep: permuted bf16 weights (+permuted fp32 biases) + encoder transpose.
// Row permutation groups outputs head-major: q=h*192+ch, k=h*192+64+ch,
// v=h*192+128+ch (qkv_w); ek=h*128+ch, ev=h*128+64+ch (ekv_w).
// ---------------------------------------------------------------------------
__global__ __launch_bounds__(256) void prep_kernel(
    const float* __restrict__ qkv_w, const float* __restrict__ ekv_w,
    const float* __restrict__ proj_w, const float* __restrict__ enc,
    const float* __restrict__ qkv_b, const float* __restrict__ ekv_b,
    u16* __restrict__ wQK, u16* __restrict__ wV, u16* __restrict__ wEK,
    u16* __restrict__ wEV, u16* __restrict__ projwb, u16* __restrict__ encT,
    float* __restrict__ bQK, float* __restrict__ bV,
    float* __restrict__ bEK, float* __restrict__ bEV) {
  int blk = blockIdx.x, tid = threadIdx.x;
  if (blk < 512) {                   // wQK: 1024 rows
    int idx = blk * 256 + tid;       // vec4 index
    int n = idx >> 7, c4 = (idx & 127) * 4;
    int which = n >> 9, h = (n >> 6) & 7, ch = n & 63;
    int src = h * 192 + which * 64 + ch;
    float4 v = *(const float4*)(qkv_w + (size_t)src * 512 + c4);
    u16x4 o; o.x = f2bf(v.x); o.y = f2bf(v.y); o.z = f2bf(v.z); o.w = f2bf(v.w);
    *(u16x4*)(wQK + (size_t)n * 512 + c4) = o;
  } else if (blk < 768) {            // wV
    int idx = (blk - 512) * 256 + tid;
    int n = idx >> 7, c4 = (idx & 127) * 4;
    int h = n >> 6, ch = n & 63;
    int src = h * 192 + 128 + ch;
    float4 v = *(const float4*)(qkv_w + (size_t)src * 512 + c4);
    u16x4 o; o.x = f2bf(v.x); o.y = f2bf(v.y); o.z = f2bf(v.z); o.w = f2bf(v.w);
    *(u16x4*)(wV + (size_t)n * 512 + c4) = o;
  } else if (blk < 1024) {           // wEK
    int idx = (blk - 768) * 256 + tid;
    int n = idx >> 7, c4 = (idx & 127) * 4;
    int h = n >> 6, ch = n & 63;
    int src = h * 128 + ch;
    float4 v = *(const float4*)(ekv_w + (size_t)src * 512 + c4);
    u16x4 o; o.x = f2bf(v.x); o.y = f2bf(v.y); o.z = f2bf(v.z); o.w = f2bf(v.w);
    *(u16x4*)(wEK + (size_t)n * 512 + c4) = o;
  } else if (blk < 1280) {           // wEV
    int idx = (blk - 1024) * 256 + tid;
    int n = idx >> 7, c4 = (idx & 127) * 4;
    int h = n >> 6, ch = n & 63;
    int src = h * 128 + 64 + ch;
    float4 v = *(const float4*)(ekv_w + (size_t)src * 512 + c4);
    u16x4 o; o.x = f2bf(v.x); o.y = f2bf(v.y); o.z = f2bf(v.z); o.w = f2bf(v.w);
    *(u16x4*)(wEV + (size_t)n * 512 + c4) = o;
  } else if (blk < 1536) {           // projwb (no permute)
    int idx = (blk - 1280) * 256 + tid;
    float4 v = ((const float4*)proj_w)[idx];
    u16x4 o; o.x = f2bf(v.x); o.y = f2bf(v.y); o.z = f2bf(v.z); o.w = f2bf(v.w);
    *(u16x4*)(projwb + (size_t)idx * 4) = o;
  } else if (blk < 2048) {           // encT: [b][128 s][512 c], zero-padded
    int idx = (blk - 1536) * 256 + tid;
    int b = idx >> 14, rem = idx & 16383;
    int s = rem >> 7, c = (rem & 127) * 4;
    u16x4 o; o.x = 0; o.y = 0; o.z = 0; o.w = 0;
    if (s < SS) {
      const float* p = enc + ((size_t)b * 512 + c) * SS + s;
      o.x = f2bf(p[0]); o.y = f2bf(p[SS]); o.z = f2bf(p[2 * SS]); o.w = f2bf(p[3 * SS]);
    }
    *(u16x4*)(encT + ((size_t)b * 128 + s) * 512 + c) = o;
  } else {                           // biases
    for (int i = tid; i < 2560; i += 256) {
      if (i < 1024) {
        int which = i >> 9, h = (i >> 6) & 7, ch = i & 63;
        bQK[i] = qkv_b[h * 192 + which * 64 + ch];
      } else if (i < 1536) {
        int j = i - 1024; int h = j >> 6, ch = j & 63;
        bV[j] = qkv_b[h * 192 + 128 + ch];
      } else if (i < 2048) {
        int j = i - 1536; int h = j >> 6, ch = j & 63;
        bEK[j] = ekv_b[h * 128 + ch];
      } else {
        int j = i - 2048; int h = j >> 6, ch = j & 63;
        bEV[j] = ekv_b[h * 128 + 64 + ch];
      }
    }
  }
}

// ---------------------------------------------------------------------------
// GroupNorm32 -> transposed bf16 output nrmT[b][t][c]. (round-3 verified)
// ---------------------------------------------------------------------------
__global__ __launch_bounds__(256) void gn_kernel(
    const float* __restrict__ x, const float* __restrict__ scale,
    const float* __restrict__ bias, u16* __restrict__ nrmT) {
  int bg = blockIdx.x;
  int b = bg >> 5, g = bg & 31;
  __shared__ unsigned short Xs[16 * 1024];
  __shared__ float red[8];
  const float4* x4 = (const float4*)(x + (size_t)bg * 16384);
  int tid = threadIdx.x;

  float s = 0.f, sq = 0.f;
#pragma unroll
  for (int i = 0; i < 16; ++i) {
    int idx = tid + 256 * i;
    float4 v = x4[idx];
    s += v.x + v.y + v.z + v.w;
    sq += v.x * v.x + v.y * v.y + v.z * v.z + v.w * v.w;
    int c = idx >> 8, t4 = (idx & 255) * 4;
    u16x4 o; o.x = f2bf(v.x); o.y = f2bf(v.y); o.z = f2bf(v.z); o.w = f2bf(v.w);
    *(u16x4*)(Xs + c * 1024 + t4) = o;
  }
#pragma unroll
  for (int off = 32; off > 0; off >>= 1) {
    s += __shfl_down(s, off, 64);
    sq += __shfl_down(sq, off, 64);
  }
  int wave = tid >> 6;
  if ((tid & 63) == 0) { red[wave] = s; red[wave + 4] = sq; }
  __syncthreads();
  float ts = red[0] + red[1] + red[2] + red[3];
  float tq = red[4] + red[5] + red[6] + red[7];
  float mu = ts * (1.0f / 16384.0f);
  float var = tq * (1.0f / 16384.0f) - mu * mu;
  float rs = rsqrtf(var + 1e-5f);

  float scv[16], biv[16];
#pragma unroll
  for (int c = 0; c < 16; ++c) {
    float ss = scale[g * 16 + c] * rs;
    scv[c] = ss;
    biv[c] = bias[g * 16 + c] - mu * ss;
  }
#pragma unroll
  for (int j = 0; j < 4; ++j) {
    int t = tid + 256 * j;
    u16x8 o0, o1;
#pragma unroll
    for (int c = 0; c < 8; ++c)
      o0[c] = f2bf(bf2f(Xs[c * 1024 + t]) * scv[c] + biv[c]);
#pragma unroll
    for (int c = 8; c < 16; ++c)
      o1[c - 8] = f2bf(bf2f(Xs[c * 1024 + t]) * scv[c] + biv[c]);
    u16* dst = nrmT + ((size_t)b * 1024 + t) * 512 + g * 16;
    *(u16x8*)dst = o0;
    *(u16x8*)(dst + 8) = o1;
  }
}

// ---------------------------------------------------------------------------
// MFMA GEMM (m97 structure), generalized batch strides.
// C[m][n] = sum_k A[bz][m][k] * B[bz][n][k] (+bias)  -- both K-contiguous.
// MODE 0: bf16 out [bz][m][n], bias[m].
// MODE 2: fp32 out + bias[m] + residual.
// MODE 3: headed transposed store: bias[n];  np=n&511, h=np>>6, ch=np&63:
//         dst(n<512?Cv:Cv2)[((bz*8+h)*Trows + m)*64 + ch]
// ---------------------------------------------------------------------------
template <int MODE>
__global__ __launch_bounds__(256) void mfma_gemm(
    const u16* __restrict__ A, const u16* __restrict__ B,
    const float* __restrict__ bias, const float* __restrict__ res,
    void* __restrict__ Cv, void* __restrict__ Cv2,
    long sA, long sB, int Cn, long Cbatch, int Trows) {
  __shared__ __align__(16) u16 As[8192];  // [128][64] swizzled
  __shared__ __align__(16) u16 Bs[8192];

  int tid = threadIdx.x;
  int lane = tid & 63, w = tid >> 6;
  int lan15 = lane & 15, quad = lane >> 4;
  int wm = w >> 1, wn = w & 1;
  int m0 = blockIdx.y * 128, n0 = blockIdx.x * 128;
  int bz = blockIdx.z;
  const u16* Ab = A + (size_t)bz * sA;
  const u16* Bb = B + (size_t)bz * sB;

  int srow = lane >> 3;
  int schunk = (lane & 7) ^ srow;
  const char* Ag = (const char*)(Ab + (size_t)(m0 + w * 32 + srow) * 512) + schunk * 16;
  const char* Bg = (const char*)(Bb + (size_t)(n0 + w * 32 + srow) * 512) + schunk * 16;
  char* Al = (char*)As + w * 4096;
  char* Bl = (char*)Bs + w * 4096;

  v4f acc[4][4] = {};

  for (int step = 0; step < 8; ++step) {
    __syncthreads();
    int kb = step * 128;
#pragma unroll
    for (int i = 0; i < 4; ++i)
      gl_lds16(Ag + kb + i * 8192, Al + i * 1024);
#pragma unroll
    for (int i = 0; i < 4; ++i)
      gl_lds16(Bg + kb + i * 8192, Bl + i * 1024);
    __syncthreads();

#pragma unroll
    for (int ksub = 0; ksub < 2; ++ksub) {
      int ch = ((ksub * 4 + quad) ^ (lan15 & 7)) * 16;
      v8s a[4], bf[4];
#pragma unroll
      for (int i = 0; i < 4; ++i)
        a[i] = *(const v8s*)((const char*)As + (wm * 64 + i * 16 + lan15) * 128 + ch);
#pragma unroll
      for (int j = 0; j < 4; ++j)
        bf[j] = *(const v8s*)((const char*)Bs + (wn * 64 + j * 16 + lan15) * 128 + ch);
#pragma unroll
      for (int i = 0; i < 4; ++i)
#pragma unroll
        for (int j = 0; j < 4; ++j)
          acc[i][j] = __builtin_amdgcn_mfma_f32_16x16x32_bf16(a[i], bf[j], acc[i][j], 0, 0, 0);
    }
  }

  if (MODE == 3) {
#pragma unroll
    for (int j = 0; j < 4; ++j) {
      int n = n0 + wn * 64 + j * 16 + lan15;
      float bv_ = bias[n];
      int np = n & 511;
      u16* dst = (u16*)((n < 512) ? Cv : Cv2);
      u16* dp = dst + ((size_t)(bz * 8 + (np >> 6)) * Trows) * 64 + (np & 63);
#pragma unroll
      for (int i = 0; i < 4; ++i) {
#pragma unroll
        for (int r = 0; r < 4; ++r) {
          int m = m0 + wm * 64 + i * 16 + quad * 4 + r;
          dp[(size_t)m * 64] = f2bf(acc[i][j][r] + bv_);
        }
      }
    }
  } else {
#pragma unroll
    for (int i = 0; i < 4; ++i) {
      int ob = m0 + wm * 64 + i * 16 + quad * 4;
#pragma unroll
      for (int r = 0; r < 4; ++r) {
        int o = ob + r;
        float bi = bias[o];
#pragma unroll
        for (int j = 0; j < 4; ++j) {
          int n = n0 + wn * 64 + j * 16 + lan15;
          if (MODE == 2) {
            float* C = (float*)Cv + (size_t)bz * Cbatch;
            C[(size_t)o * Cn + n] = acc[i][j][r] + bi +
                res[(size_t)bz * Cbatch + (size_t)o * Cn + n];
          } else {
            u16* C = (u16*)Cv + (size_t)bz * Cbatch;
            C[(size_t)o * Cn + n] = f2bf(acc[i][j][r] + bi);
          }
        }
      }
    }
  }
}

// ---------------------------------------------------------------------------
// MFMA flash attention v2. Block = 4 waves; wave owns 32 t-rows; block 128 t.
// Inputs: Qh/Kh [bh][1024][64], Vb [bh][64][1024], ekh [bh][128][64],
//         evh [bh][64][128] (all bf16). 18 s-chunks of 64 (2 enc + 16 self).
// All staging via global_load_lds w/ XOR chunk swizzle; softmax in exp2-domain
// with DPP reductions; P per-wave in LDS (no cross-wave barrier needed).
// ---------------------------------------------------------------------------
#define AOFF_Q 0          // [128][64] u16  16384
#define AOFF_K 16384      // [64][64]  u16   8192
#define AOFF_V 24576      // [64][64]  u16   8192
#define AOFF_P 32768      // 4 x [32][72] u16 18432
#define AOFF_M 51200      // 128 f32
#define ASMEM  51712

__global__ __launch_bounds__(256) void attn_kernel(
    const u16* __restrict__ Qh, const u16* __restrict__ Kh,
    const u16* __restrict__ Vb, const u16* __restrict__ ekh,
    const u16* __restrict__ evh, const int* __restrict__ mask,
    u16* __restrict__ attnT) {
  __shared__ __align__(16) unsigned char smem[ASMEM];
  u16* Qs = (u16*)(smem + AOFF_Q);
  u16* Ks = (u16*)(smem + AOFF_K);
  u16* Vs = (u16*)(smem + AOFF_V);
  float* AM = (float*)(smem + AOFF_M);

  int bh = blockIdx.x;            // fastest -> same bh's t-tiles share XCD
  int b = bh >> 3, h = bh & 7;
  int t0 = blockIdx.y * 128;
  int tid = threadIdx.x;
  int lane = tid & 63, w = tid >> 6;
  int lan15 = lane & 15, quad = lane >> 4;
  int r8 = lane >> 3, c8 = lane & 7;
  int swB = (c8 ^ r8) * 16;       // byte swizzle offset for staging

  const u16* Qb = Qh + (size_t)bh * 1024 * 64;
  const u16* Kb = Kh + (size_t)bh * 1024 * 64;
  const u16* Vbp = Vb + (size_t)bh * 64 * 1024;
  const u16* ekb = ekh + (size_t)bh * 128 * 64;
  const u16* evb = evh + (size_t)bh * 64 * 128;
  u16* Psw = (u16*)(smem + AOFF_P) + w * 2304;

  // mask row (exp2-domain: pre-scaled by log2 e)
  if (tid < 128) {
    float v;
    if (tid < SS) v = (mask[h * SS + tid] != 0) ? 0.f : -14426.95f;
    else v = -1e30f;
    AM[tid] = v;
  }
  // stage Q once: [128 t][64 ch]
#pragma unroll
  for (int i = 0; i < 4; ++i)
    gl_lds16((const char*)(Qb + (size_t)(t0 + w * 32 + i * 8 + r8) * 64) + swB,
             (char*)Qs + (w * 32 + i * 8) * 128);
  __syncthreads();

  // hoist Q A-frags
  v8s aq[2][2];
#pragma unroll
  for (int mt = 0; mt < 2; ++mt)
#pragma unroll
    for (int ks = 0; ks < 2; ++ks)
      aq[mt][ks] = *(const v8s*)((const char*)Qs +
          (w * 32 + mt * 16 + lan15) * 128 + (((ks * 4 + quad) ^ (lan15 & 7)) * 16));

  v4f O[2][4] = {};
  float mst[2][4], lst[2][4];
#pragma unroll
  for (int mt = 0; mt < 2; ++mt)
#pragma unroll
    for (int r = 0; r < 4; ++r) { mst[mt][r] = -1e30f; lst[mt][r] = 0.f; }

  const float SCL = 0.125f * 1.44269504f;

  for (int c = 0; c < 18; ++c) {
    bool enc = (c < 2);
    const u16* kptr = enc ? (ekb + c * 64 * 64) : (Kb + (size_t)(c - 2) * 64 * 64);
    const u16* vptr = enc ? (evb + c * 64) : (Vbp + (c - 2) * 64);
    long vstr = enc ? 128 : 1024;

    __syncthreads();
#pragma unroll
    for (int i = 0; i < 2; ++i)
      gl_lds16((const char*)(kptr + (size_t)(w * 16 + i * 8 + r8) * 64) + swB,
               (char*)Ks + (w * 16 + i * 8) * 128);
#pragma unroll
    for (int i = 0; i < 2; ++i)
      gl_lds16((const char*)(vptr + (size_t)(w * 16 + i * 8 + r8) * vstr) + swB,
               (char*)Vs + (w * 16 + i * 8) * 128);
    __syncthreads();

    // QK^T: S[32 t][64 s] per wave
    v4f S[2][4] = {};
#pragma unroll
    for (int ks = 0; ks < 2; ++ks) {
      int cofs = ((ks * 4 + quad) ^ (lan15 & 7)) * 16;
      v8s bk[4];
#pragma unroll
      for (int nt = 0; nt < 4; ++nt)
        bk[nt] = *(const v8s*)((const char*)Ks + (nt * 16 + lan15) * 128 + cofs);
#pragma unroll
      for (int mt = 0; mt < 2; ++mt)
#pragma unroll
        for (int nt = 0; nt < 4; ++nt)
          S[mt][nt] = __builtin_amdgcn_mfma_f32_16x16x32_bf16(aq[mt][ks], bk[nt], S[mt][nt], 0, 0, 0);
    }

    // softmax (exp2-domain)
    float add_[4];
#pragma unroll
    for (int nt = 0; nt < 4; ++nt)
      add_[nt] = enc ? AM[c * 64 + nt * 16 + lan15] : 0.f;
    float p[2][4][4];
#pragma unroll
    for (int mt = 0; mt < 2; ++mt)
#pragma unroll
      for (int nt = 0; nt < 4; ++nt)
#pragma unroll
        for (int r = 0; r < 4; ++r)
          p[mt][nt][r] = S[mt][nt][r] * SCL + add_[nt];

#pragma unroll
    for (int mt = 0; mt < 2; ++mt)
#pragma unroll
      for (int r = 0; r < 4; ++r) {
        float mx = fmaxf(fmaxf(p[mt][0][r], p[mt][1][r]), fmaxf(p[mt][2][r], p[mt][3][r]));
        mx = red16max(mx);
        float nm = fmaxf(mst[mt][r], mx);
        float al = exp2f(mst[mt][r] - nm);
        mst[mt][r] = nm;
        float s0 = 0.f;
#pragma unroll
        for (int nt = 0; nt < 4; ++nt) {
          float e = exp2f(p[mt][nt][r] - nm);
          p[mt][nt][r] = e;
          s0 += e;
        }
        s0 = red16sum(s0);
        lst[mt][r] = lst[mt][r] * al + s0;
#pragma unroll
        for (int nc = 0; nc < 4; ++nc) O[mt][nc][r] *= al;
      }

    // P -> per-wave LDS (A-layout rows=t, cols=s, stride 72)
#pragma unroll
    for (int mt = 0; mt < 2; ++mt)
#pragma unroll
      for (int nt = 0; nt < 4; ++nt)
#pragma unroll
        for (int r = 0; r < 4; ++r)
          Psw[(mt * 16 + quad * 4 + r) * 72 + nt * 16 + lan15] = f2bf(p[mt][nt][r]);

    // PV: O[32 t][64 c] += P[32][64] * V^T
#pragma unroll
    for (int ks = 0; ks < 2; ++ks) {
      int cofs = ((ks * 4 + quad) ^ (lan15 & 7)) * 16;
      v8s ap[2], bv[4];
#pragma unroll
      for (int mt = 0; mt < 2; ++mt)
        ap[mt] = *(const v8s*)((const char*)Psw + (mt * 16 + lan15) * 144 + ks * 64 + quad * 16);
#pragma unroll
      for (int nc = 0; nc < 4; ++nc)
        bv[nc] = *(const v8s*)((const char*)Vs + (nc * 16 + lan15) * 128 + cofs);
#pragma unroll
      for (int mt = 0; mt < 2; ++mt)
#pragma unroll
        for (int nc = 0; nc < 4; ++nc)
          O[mt][nc] = __builtin_amdgcn_mfma_f32_16x16x32_bf16(ap[mt], bv[nc], O[mt][nc], 0, 0, 0);
    }
  }

  // epilogue: normalize, transpose via LDS (overlays Q/K/V/P), bf16 store
  float inv[2][4];
#pragma unroll
  for (int mt = 0; mt < 2; ++mt)
#pragma unroll
    for (int r = 0; r < 4; ++r) inv[mt][r] = 1.0f / lst[mt][r];
  __syncthreads();
  float* Ot = (float*)smem;   // [128][68]
#pragma unroll
  for (int mt = 0; mt < 2; ++mt)
#pragma unroll
    for (int nc = 0; nc < 4; ++nc)
#pragma unroll
      for (int r = 0; r < 4; ++r)
        Ot[(w * 32 + mt * 16 + quad * 4 + r) * 68 + nc * 16 + lan15] =
            O[mt][nc][r] * inv[mt][r];
  __syncthreads();
  {
    int row = tid >> 1, seg = (tid & 1) * 32;
    const float* src = Ot + row * 68 + seg;
    u16* dp = attnT + ((size_t)b * 1024 + t0 + row) * 512 + h * 64 + seg;
#pragma unroll
    for (int g = 0; g < 4; ++g) {
      u16x8 o;
#pragma unroll
      for (int k = 0; k < 8; ++k) o[k] = f2bf(src[g * 8 + k]);
      *(u16x8*)(dp + g * 8) = o;
    }
  }
}

// ---------------------------------------------------------------------------
extern "C" void kernel_launch(void* const* d_in, const int* in_sizes, int n_in,
                              void* d_out, int out_size, void* d_ws, size_t ws_size,
                              hipStream_t stream) {
  const float* x       = (const float*)d_in[0];
  const float* enc     = (const float*)d_in[1];
  const int*   mask    = (const int*)d_in[2];
  const float* nscale  = (const float*)d_in[3];
  const float* nbias   = (const float*)d_in[4];
  const float* qkv_w   = (const float*)d_in[5];
  const float* qkv_b   = (const float*)d_in[6];
  const float* ekv_w   = (const float*)d_in[7];
  const float* ekv_b   = (const float*)d_in[8];
  const float* proj_w  = (const float*)d_in[9];
  const float* proj_b  = (const float*)d_in[10];
  float* out = (float*)d_out;

  char* ws = (char*)d_ws;
  const size_t MiB = 1048576;
  u16* nrmT   = (u16*)(ws);              // [8][1024][512]
  u16* Qh     = (u16*)(ws + 8  * MiB);   // [64][1024][64]
  u16* Kh     = (u16*)(ws + 16 * MiB);   // [64][1024][64]
  u16* Vb     = (u16*)(ws + 24 * MiB);   // [64][64][1024]
  u16* attnT  = (u16*)(ws + 32 * MiB);   // [8][1024][512]
  u16* ekh    = (u16*)(ws + 40 * MiB);   // [64][128][64]
  u16* evh    = (u16*)(ws + 41 * MiB);   // [64][64][128]
  u16* encT   = (u16*)(ws + 42 * MiB);   // [8][128][512]
  u16* wQK    = (u16*)(ws + 43 * MiB);   // [1024][512]
  u16* wV     = (u16*)(ws + 44 * MiB);   // [512][512]
  u16* wEK    = (u16*)(ws + 44 * MiB + 524288);
  u16* wEV    = (u16*)(ws + 45 * MiB);
  u16* projwb = (u16*)(ws + 45 * MiB + 524288);
  float* bQK  = (float*)(ws + 46 * MiB);
  float* bV   = (float*)(ws + 46 * MiB + 4096);
  float* bEK  = (float*)(ws + 46 * MiB + 6144);
  float* bEV  = (float*)(ws + 46 * MiB + 8192);

  // 1) prep: permuted bf16 weights + biases + encoder transpose
  prep_kernel<<<dim3(2049), dim3(256), 0, stream>>>(
      qkv_w, ekv_w, proj_w, enc, qkv_b, ekv_b,
      wQK, wV, wEK, wEV, projwb, encT, bQK, bV, bEK, bEV);

  // 2) GroupNorm32 -> nrmT [b][t][512]
  gn_kernel<<<dim3(BB * 32), dim3(256), 0, stream>>>(x, nscale, nbias, nrmT);

  // 3) Q,K (swapped operands): D[t][o] -> Qh/Kh [bh][1024][64]
  mfma_gemm<3><<<dim3(8, 8, BB), dim3(256), 0, stream>>>(
      nrmT, wQK, bQK, nullptr, Qh, Kh, (long)1024 * 512, 0, 0, 0, 1024);

  // 4) V: D[o][t] -> Vb [bh][64][1024]
  mfma_gemm<0><<<dim3(8, 4, BB), dim3(256), 0, stream>>>(
      wV, nrmT, bV, nullptr, Vb, nullptr, 0, (long)1024 * 512, 1024, (long)512 * 1024, 0);

  // 5) ek (swapped): D[s][o] -> ekh [bh][128][64]
  mfma_gemm<3><<<dim3(4, 1, BB), dim3(256), 0, stream>>>(
      encT, wEK, bEK, nullptr, ekh, ekh, (long)128 * 512, 0, 0, 0, 128);

  // 6) ev: D[o][s] -> evh [bh][64][128]
  mfma_gemm<0><<<dim3(1, 4, BB), dim3(256), 0, stream>>>(
      wEV, encT, bEV, nullptr, evh, nullptr, 0, (long)128 * 512, 128, (long)512 * 128, 0);

  // 7) attention -> attnT [b][t][512]
  attn_kernel<<<dim3(64, 8), dim3(256), 0, stream>>>(
      Qh, Kh, Vb, ekh, evh, mask, attnT);

  // 8) out = x + proj_w @ attn
  mfma_gemm<2><<<dim3(8, 4, BB), dim3(256), 0, stream>>>(
      projwb, attnT, proj_b, x, out, nullptr, 0, (long)1024 * 512, 1024, (long)512 * 1024, 0);
}

// Round 5
// 202.079 us; speedup vs baseline: 65.5263x; 1.1595x over previous
//
#include <hip/hip_runtime.h>
#include <math.h>

#define BB 8
#define TT 1024
#define SS 77

typedef short v8s __attribute__((ext_vector_type(8)));
typedef float v4f __attribute__((ext_vector_type(4)));
typedef unsigned short u16x4 __attribute__((ext_vector_type(4)));
typedef unsigned short u16x8 __attribute__((ext_vector_type(8)));
typedef unsigned short u16;

// fold 64^-0.25 * sqrt(log2 e) into q and k weights -> logits in exp2-domain
#define SCALEF 0.424660891f
#define MASKNEG (-14426.95f)   // -10000 * log2(e)

__device__ __forceinline__ u16 f2bf(float f) {
  unsigned u = __float_as_uint(f);
  u = (u + 0x7fffu + ((u >> 16) & 1u)) >> 16;
  return (u16)u;
}
__device__ __forceinline__ u16 hi16(float f) {
  return (u16)(__float_as_uint(f) >> 16);
}
__device__ __forceinline__ float bf2f(u16 u) {
  return __uint_as_float(((unsigned)u) << 16);
}
__device__ __forceinline__ void gl_lds16(const void* g, void* l) {
  __builtin_amdgcn_global_load_lds(
      (const __attribute__((address_space(1))) void*)g,
      (__attribute__((address_space(3))) void*)l, 16, 0, 0);
}
__device__ __forceinline__ float red16sum(float v) {
  int i;
  i = __builtin_amdgcn_update_dpp(__float_as_int(v), __float_as_int(v), 0xB1, 0xF, 0xF, true);
  v += __int_as_float(i);
  i = __builtin_amdgcn_update_dpp(__float_as_int(v), __float_as_int(v), 0x4E, 0xF, 0xF, true);
  v += __int_as_float(i);
  i = __builtin_amdgcn_ds_swizzle(__float_as_int(v), 0x101F);
  v += __int_as_float(i);
  i = __builtin_amdgcn_update_dpp(__float_as_int(v), __float_as_int(v), 0x128, 0xF, 0xF, true);
  v += __int_as_float(i);
  return v;
}

// ---------------------------------------------------------------------------
// Fused GroupNorm (blocks 0..255) + prep (blocks 256..2304).
// gn: one block per (b,g) -> nrmT[b][t][512] bf16.
// prep: permuted/scaled bf16 weights + biases + encoder transpose (pad 128).
// ---------------------------------------------------------------------------
__global__ __launch_bounds__(256) void prep_gn_kernel(
    const float* __restrict__ x, const float* __restrict__ scale,
    const float* __restrict__ bias, u16* __restrict__ nrmT,
    const float* __restrict__ qkv_w, const float* __restrict__ ekv_w,
    const float* __restrict__ proj_w, const float* __restrict__ enc,
    const float* __restrict__ qkv_b, const float* __restrict__ ekv_b,
    u16* __restrict__ wQK, u16* __restrict__ wV, u16* __restrict__ wEK,
    u16* __restrict__ wEV, u16* __restrict__ projwb, u16* __restrict__ encT,
    float* __restrict__ bQK, float* __restrict__ bV,
    float* __restrict__ bEK, float* __restrict__ bEV) {
  __shared__ u16 Xs[16 * 1024];
  __shared__ float red[8];
  int blk = blockIdx.x, tid = threadIdx.x;

  if (blk < 256) {             // ---- GroupNorm path ----
    int bg = blk;
    int b = bg >> 5, g = bg & 31;
    const float4* x4 = (const float4*)(x + (size_t)bg * 16384);
    float s = 0.f, sq = 0.f;
#pragma unroll
    for (int i = 0; i < 16; ++i) {
      int idx = tid + 256 * i;
      float4 v = x4[idx];
      s += v.x + v.y + v.z + v.w;
      sq += v.x * v.x + v.y * v.y + v.z * v.z + v.w * v.w;
      int c = idx >> 8, t4 = (idx & 255) * 4;
      u16x4 o; o.x = f2bf(v.x); o.y = f2bf(v.y); o.z = f2bf(v.z); o.w = f2bf(v.w);
      *(u16x4*)(Xs + c * 1024 + t4) = o;
    }
#pragma unroll
    for (int off = 32; off > 0; off >>= 1) {
      s += __shfl_down(s, off, 64);
      sq += __shfl_down(sq, off, 64);
    }
    int wave = tid >> 6;
    if ((tid & 63) == 0) { red[wave] = s; red[wave + 4] = sq; }
    __syncthreads();
    float ts = red[0] + red[1] + red[2] + red[3];
    float tq = red[4] + red[5] + red[6] + red[7];
    float mu = ts * (1.0f / 16384.0f);
    float var = tq * (1.0f / 16384.0f) - mu * mu;
    float rs = rsqrtf(var + 1e-5f);
    float scv[16], biv[16];
#pragma unroll
    for (int c = 0; c < 16; ++c) {
      float ss = scale[g * 16 + c] * rs;
      scv[c] = ss;
      biv[c] = bias[g * 16 + c] - mu * ss;
    }
#pragma unroll
    for (int j = 0; j < 4; ++j) {
      int t = tid + 256 * j;
      u16x8 o0, o1;
#pragma unroll
      for (int c = 0; c < 8; ++c)  o0[c] = f2bf(bf2f(Xs[c * 1024 + t]) * scv[c] + biv[c]);
#pragma unroll
      for (int c = 8; c < 16; ++c) o1[c - 8] = f2bf(bf2f(Xs[c * 1024 + t]) * scv[c] + biv[c]);
      u16* dst = nrmT + ((size_t)b * 1024 + t) * 512 + g * 16;
      *(u16x8*)dst = o0;
      *(u16x8*)(dst + 8) = o1;
    }
    return;
  }

  int p = blk - 256;           // ---- prep path ----
  if (p < 512) {               // wQK (scaled)
    int idx = p * 256 + tid;
    int n = idx >> 7, c4 = (idx & 127) * 4;
    int which = n >> 9, h = (n >> 6) & 7, ch = n & 63;
    int src = h * 192 + which * 64 + ch;
    float4 v = *(const float4*)(qkv_w + (size_t)src * 512 + c4);
    u16x4 o; o.x = f2bf(v.x * SCALEF); o.y = f2bf(v.y * SCALEF);
    o.z = f2bf(v.z * SCALEF); o.w = f2bf(v.w * SCALEF);
    *(u16x4*)(wQK + (size_t)n * 512 + c4) = o;
  } else if (p < 768) {        // wV
    int idx = (p - 512) * 256 + tid;
    int n = idx >> 7, c4 = (idx & 127) * 4;
    int h = n >> 6, ch = n & 63;
    int src = h * 192 + 128 + ch;
    float4 v = *(const float4*)(qkv_w + (size_t)src * 512 + c4);
    u16x4 o; o.x = f2bf(v.x); o.y = f2bf(v.y); o.z = f2bf(v.z); o.w = f2bf(v.w);
    *(u16x4*)(wV + (size_t)n * 512 + c4) = o;
  } else if (p < 1024) {       // wEK (scaled)
    int idx = (p - 768) * 256 + tid;
    int n = idx >> 7, c4 = (idx & 127) * 4;
    int h = n >> 6, ch = n & 63;
    int src = h * 128 + ch;
    float4 v = *(const float4*)(ekv_w + (size_t)src * 512 + c4);
    u16x4 o; o.x = f2bf(v.x * SCALEF); o.y = f2bf(v.y * SCALEF);
    o.z = f2bf(v.z * SCALEF); o.w = f2bf(v.w * SCALEF);
    *(u16x4*)(wEK + (size_t)n * 512 + c4) = o;
  } else if (p < 1280) {       // wEV
    int idx = (p - 1024) * 256 + tid;
    int n = idx >> 7, c4 = (idx & 127) * 4;
    int h = n >> 6, ch = n & 63;
    int src = h * 128 + 64 + ch;
    float4 v = *(const float4*)(ekv_w + (size_t)src * 512 + c4);
    u16x4 o; o.x = f2bf(v.x); o.y = f2bf(v.y); o.z = f2bf(v.z); o.w = f2bf(v.w);
    *(u16x4*)(wEV + (size_t)n * 512 + c4) = o;
  } else if (p < 1536) {       // projwb
    int idx = (p - 1280) * 256 + tid;
    float4 v = ((const float4*)proj_w)[idx];
    u16x4 o; o.x = f2bf(v.x); o.y = f2bf(v.y); o.z = f2bf(v.z); o.w = f2bf(v.w);
    *(u16x4*)(projwb + (size_t)idx * 4) = o;
  } else if (p < 2048) {       // encT [b][128][512], zero-padded
    int idx = (p - 1536) * 256 + tid;
    int b = idx >> 14, rem = idx & 16383;
    int s = rem >> 7, c = (rem & 127) * 4;
    u16x4 o; o.x = 0; o.y = 0; o.z = 0; o.w = 0;
    if (s < SS) {
      const float* pp = enc + ((size_t)b * 512 + c) * SS + s;
      o.x = f2bf(pp[0]); o.y = f2bf(pp[SS]); o.z = f2bf(pp[2 * SS]); o.w = f2bf(pp[3 * SS]);
    }
    *(u16x4*)(encT + ((size_t)b * 128 + s) * 512 + c) = o;
  } else {                     // biases (permuted; q/k scaled)
    for (int i = tid; i < 2560; i += 256) {
      if (i < 1024) {
        int which = i >> 9, h = (i >> 6) & 7, ch = i & 63;
        bQK[i] = qkv_b[h * 192 + which * 64 + ch] * SCALEF;
      } else if (i < 1536) {
        int j = i - 1024; int h = j >> 6, ch = j & 63;
        bV[j] = qkv_b[h * 192 + 128 + ch];
      } else if (i < 2048) {
        int j = i - 1536; int h = j >> 6, ch = j & 63;
        bEK[j] = ekv_b[h * 128 + ch] * SCALEF;
      } else {
        int j = i - 2048; int h = j >> 6, ch = j & 63;
        bEV[j] = ekv_b[h * 128 + 64 + ch];
      }
    }
  }
}

// ---------------------------------------------------------------------------
// MFMA GEMM, m97 structure. C = A[m][k]*B[n][k]^T + bias. K=512.
// MODE 0: bf16 out C[bz][m][Cn] at col offset coff, bias[m].
// MODE 2: fp32 out + bias[m] + residual.
// MODE 3: transposed head-major store via LDS: bias[n]; n<512 -> dstA else B:
//         dst[((bz*8 + (n&511)>>6)*Trows + off + m)*64 + (n&63)]
// ---------------------------------------------------------------------------
template <int MODE>
__global__ __launch_bounds__(256) void mfma_gemm(
    const u16* __restrict__ A, const u16* __restrict__ B,
    const float* __restrict__ bias, const float* __restrict__ res,
    u16* __restrict__ CvA, u16* __restrict__ CvB, float* __restrict__ Cf,
    long sA, long sB, int Cn, int coff, long Cbatch,
    int TrA, int offA, int TrB, int offB) {
  __shared__ __align__(16) u16 SH[16384];
  u16* As = SH;
  u16* Bs = SH + 8192;

  int tid = threadIdx.x;
  int lane = tid & 63, w = tid >> 6;
  int lan15 = lane & 15, quad = lane >> 4;
  int wm = w >> 1, wn = w & 1;
  int m0 = blockIdx.y * 128, n0 = blockIdx.x * 128;
  int bz = blockIdx.z;
  const u16* Ab = A + (size_t)bz * sA;
  const u16* Bb = B + (size_t)bz * sB;

  int srow = lane >> 3;
  int schunk = (lane & 7) ^ srow;
  const char* Ag = (const char*)(Ab + (size_t)(m0 + w * 32 + srow) * 512) + schunk * 16;
  const char* Bg = (const char*)(Bb + (size_t)(n0 + w * 32 + srow) * 512) + schunk * 16;
  char* Al = (char*)As + w * 4096;
  char* Bl = (char*)Bs + w * 4096;

  v4f acc[4][4] = {};

  for (int step = 0; step < 8; ++step) {
    __syncthreads();
    int kb = step * 128;
#pragma unroll
    for (int i = 0; i < 4; ++i) gl_lds16(Ag + kb + i * 8192, Al + i * 1024);
#pragma unroll
    for (int i = 0; i < 4; ++i) gl_lds16(Bg + kb + i * 8192, Bl + i * 1024);
    __syncthreads();

#pragma unroll
    for (int ksub = 0; ksub < 2; ++ksub) {
      int ch = ((ksub * 4 + quad) ^ (lan15 & 7)) * 16;
      v8s a[4], bf[4];
#pragma unroll
      for (int i = 0; i < 4; ++i)
        a[i] = *(const v8s*)((const char*)As + (wm * 64 + i * 16 + lan15) * 128 + ch);
#pragma unroll
      for (int j = 0; j < 4; ++j)
        bf[j] = *(const v8s*)((const char*)Bs + (wn * 64 + j * 16 + lan15) * 128 + ch);
#pragma unroll
      for (int i = 0; i < 4; ++i)
#pragma unroll
        for (int j = 0; j < 4; ++j)
          acc[i][j] = __builtin_amdgcn_mfma_f32_16x16x32_bf16(a[i], bf[j], acc[i][j], 0, 0, 0);
    }
  }

  if (MODE == 3) {
    u16* Tr = SH;              // [128][72] bf16
    for (int ph = 0; ph < 2; ++ph) {
      __syncthreads();
      if (wn == ph) {
#pragma unroll
        for (int j = 0; j < 4; ++j) {
          int n = n0 + wn * 64 + j * 16 + lan15;
          float bv_ = bias[n];
#pragma unroll
          for (int i = 0; i < 4; ++i)
#pragma unroll
            for (int r = 0; r < 4; ++r)
              Tr[(wm * 64 + i * 16 + quad * 4 + r) * 72 + j * 16 + lan15] =
                  f2bf(acc[i][j][r] + bv_);
        }
      }
      __syncthreads();
      int nb = n0 + ph * 64;
      u16* dst = (nb < 512) ? CvA : CvB;
      int Trows = (nb < 512) ? TrA : TrB;
      int roff  = (nb < 512) ? offA : offB;
      int hh = (nb & 511) >> 6;
      int row = tid >> 1, seg = (tid & 1) * 32;
      u16* dp = dst + ((size_t)(bz * 8 + hh) * Trows + roff + m0 + row) * 64 + seg;
#pragma unroll
      for (int g = 0; g < 4; ++g)
        *(u16x8*)(dp + g * 8) = *(const u16x8*)(Tr + row * 72 + seg + g * 8);
    }
  } else {
#pragma unroll
    for (int i = 0; i < 4; ++i) {
      int ob = m0 + wm * 64 + i * 16 + quad * 4;
#pragma unroll
      for (int r = 0; r < 4; ++r) {
        int o = ob + r;
        float bi = bias[o];
#pragma unroll
        for (int j = 0; j < 4; ++j) {
          int n = n0 + wn * 64 + j * 16 + lan15;
          if (MODE == 2) {
            float* C = Cf + (size_t)bz * Cbatch;
            C[(size_t)o * Cn + n] = acc[i][j][r] + bi +
                res[(size_t)bz * Cbatch + (size_t)o * Cn + n];
          } else {
            u16* C = CvA + (size_t)bz * Cbatch;
            C[(size_t)o * Cn + coff + n] = f2bf(acc[i][j][r] + bi);
          }
        }
      }
    }
  }
}

// ---------------------------------------------------------------------------
// MFMA flash attention v3: fixed-max exp2 softmax, K/V double-buffer,
// 1 barrier/chunk. Block = 4 waves x 32 t = 128 t; grid (64 bh, 8).
// Kfull [bh][1152][64], Vfull [bh][64][1152]; 18 chunks of 64.
// ---------------------------------------------------------------------------
#define AOFF_K 0           // 2 x 8192
#define AOFF_V 16384       // 2 x 8192
#define AOFF_P 32768       // 4 waves x 4608 (Q overlay + P)
#define AOFF_AM 51200
#define ASMEM  51712

__global__ __launch_bounds__(256) void attn_kernel(
    const u16* __restrict__ Qh, const u16* __restrict__ Kf,
    const u16* __restrict__ Vf, const int* __restrict__ mask,
    u16* __restrict__ attnT) {
  __shared__ __align__(16) unsigned char smem[ASMEM];
  float* AM = (float*)(smem + AOFF_AM);

  int bh = blockIdx.x, b = bh >> 3, h = bh & 7;
  int t0 = blockIdx.y * 128;
  int tid = threadIdx.x;
  int lane = tid & 63, w = tid >> 6;
  int lan15 = lane & 15, quad = lane >> 4;
  int r8 = lane >> 3, c8 = lane & 7;
  int swE = (c8 ^ r8) * 8;   // staging source swizzle (elements)

  const u16* Qb = Qh + (size_t)bh * 1024 * 64;
  const u16* Kb = Kf + (size_t)bh * 1152 * 64;
  const u16* Vb = Vf + (size_t)bh * 64 * 1152;
  char* Pw = (char*)smem + AOFF_P + w * 4608;   // wave-private Q/P region

  if (tid < 128)
    AM[tid] = (tid < SS) ? ((mask[h * SS + tid] != 0) ? 0.f : MASKNEG) : -1e30f;

  // stage Q (private region) + chunk 0 K/V
#pragma unroll
  for (int i = 0; i < 4; ++i)
    gl_lds16(Qb + (size_t)(t0 + w * 32 + i * 8 + r8) * 64 + swE, Pw + i * 1024);
#pragma unroll
  for (int i = 0; i < 2; ++i) {
    int row = w * 16 + i * 8;
    gl_lds16(Kb + (size_t)(row + r8) * 64 + swE, (char*)smem + AOFF_K + row * 128);
    gl_lds16(Vb + (size_t)(row + r8) * 1152 + swE, (char*)smem + AOFF_V + row * 128);
  }
  __syncthreads();

  v8s aq[2][2];
#pragma unroll
  for (int mt = 0; mt < 2; ++mt)
#pragma unroll
    for (int ks = 0; ks < 2; ++ks)
      aq[mt][ks] = *(const v8s*)(Pw + (mt * 16 + lan15) * 128 +
                                 (((ks * 4 + quad) ^ (lan15 & 7)) * 16));

  v4f O[2][4] = {};
  float lsum[2][4] = {};

  for (int c = 0; c < 18; ++c) {
    int cur = c & 1;
    if (c < 17) {
      int nb = cur ^ 1;
#pragma unroll
      for (int i = 0; i < 2; ++i) {
        int row = w * 16 + i * 8;
        gl_lds16(Kb + (size_t)((c + 1) * 64 + row + r8) * 64 + swE,
                 (char*)smem + AOFF_K + nb * 8192 + row * 128);
        gl_lds16(Vb + (size_t)(row + r8) * 1152 + (c + 1) * 64 + swE,
                 (char*)smem + AOFF_V + nb * 8192 + row * 128);
      }
    }
    const char* Kc = (const char*)smem + AOFF_K + cur * 8192;
    const char* Vc = (const char*)smem + AOFF_V + cur * 8192;

    // QK^T (logits already in exp2-domain via folded weight scale)
    v4f S[2][4] = {};
#pragma unroll
    for (int ks = 0; ks < 2; ++ks) {
      int cofs = ((ks * 4 + quad) ^ (lan15 & 7)) * 16;
      v8s bk[4];
#pragma unroll
      for (int nt = 0; nt < 4; ++nt)
        bk[nt] = *(const v8s*)(Kc + (nt * 16 + lan15) * 128 + cofs);
#pragma unroll
      for (int mt = 0; mt < 2; ++mt)
#pragma unroll
        for (int nt = 0; nt < 4; ++nt)
          S[mt][nt] = __builtin_amdgcn_mfma_f32_16x16x32_bf16(aq[mt][ks], bk[nt], S[mt][nt], 0, 0, 0);
    }

    float add_[4] = {0.f, 0.f, 0.f, 0.f};
    if (c < 2) {
#pragma unroll
      for (int nt = 0; nt < 4; ++nt) add_[nt] = AM[c * 64 + nt * 16 + lan15];
    }
    u16* Pu = (u16*)Pw;
#pragma unroll
    for (int mt = 0; mt < 2; ++mt)
#pragma unroll
      for (int r = 0; r < 4; ++r) {
        float e0 = __builtin_amdgcn_exp2f(S[mt][0][r] + add_[0]);
        float e1 = __builtin_amdgcn_exp2f(S[mt][1][r] + add_[1]);
        float e2 = __builtin_amdgcn_exp2f(S[mt][2][r] + add_[2]);
        float e3 = __builtin_amdgcn_exp2f(S[mt][3][r] + add_[3]);
        int rw = (mt * 16 + quad * 4 + r) * 72 + lan15;
        Pu[rw] = hi16(e0); Pu[rw + 16] = hi16(e1);
        Pu[rw + 32] = hi16(e2); Pu[rw + 48] = hi16(e3);
        lsum[mt][r] += (e0 + e1) + (e2 + e3);
      }

    // PV
#pragma unroll
    for (int ks = 0; ks < 2; ++ks) {
      int cofs = ((ks * 4 + quad) ^ (lan15 & 7)) * 16;
      v8s ap[2], bv[4];
#pragma unroll
      for (int mt = 0; mt < 2; ++mt)
        ap[mt] = *(const v8s*)(Pw + (mt * 16 + lan15) * 144 + ks * 64 + quad * 16);
#pragma unroll
      for (int nc = 0; nc < 4; ++nc)
        bv[nc] = *(const v8s*)(Vc + (nc * 16 + lan15) * 128 + cofs);
#pragma unroll
      for (int mt = 0; mt < 2; ++mt)
#pragma unroll
        for (int nc = 0; nc < 4; ++nc)
          O[mt][nc] = __builtin_amdgcn_mfma_f32_16x16x32_bf16(ap[mt], bv[nc], O[mt][nc], 0, 0, 0);
    }
    __syncthreads();
  }

  float inv[2][4];
#pragma unroll
  for (int mt = 0; mt < 2; ++mt)
#pragma unroll
    for (int r = 0; r < 4; ++r) inv[mt][r] = 1.0f / red16sum(lsum[mt][r]);

  float* Ot = (float*)smem;    // [128][68] f32 overlay
#pragma unroll
  for (int mt = 0; mt < 2; ++mt)
#pragma unroll
    for (int nc = 0; nc < 4; ++nc)
#pragma unroll
      for (int r = 0; r < 4; ++r)
        Ot[(w * 32 + mt * 16 + quad * 4 + r) * 68 + nc * 16 + lan15] =
            O[mt][nc][r] * inv[mt][r];
  __syncthreads();
  {
    int row = tid >> 1, seg = (tid & 1) * 32;
    const float* src = Ot + row * 68 + seg;
    u16* dp = attnT + ((size_t)b * 1024 + t0 + row) * 512 + h * 64 + seg;
#pragma unroll
    for (int g = 0; g < 4; ++g) {
      u16x8 o;
#pragma unroll
      for (int k = 0; k < 8; ++k) o[k] = f2bf(src[g * 8 + k]);
      *(u16x8*)(dp + g * 8) = o;
    }
  }
}

// ---------------------------------------------------------------------------
extern "C" void kernel_launch(void* const* d_in, const int* in_sizes, int n_in,
                              void* d_out, int out_size, void* d_ws, size_t ws_size,
                              hipStream_t stream) {
  const float* x       = (const float*)d_in[0];
  const float* enc     = (const float*)d_in[1];
  const int*   mask    = (const int*)d_in[2];
  const float* nscale  = (const float*)d_in[3];
  const float* nbias   = (const float*)d_in[4];
  const float* qkv_w   = (const float*)d_in[5];
  const float* qkv_b   = (const float*)d_in[6];
  const float* ekv_w   = (const float*)d_in[7];
  const float* ekv_b   = (const float*)d_in[8];
  const float* proj_w  = (const float*)d_in[9];
  const float* proj_b  = (const float*)d_in[10];
  float* out = (float*)d_out;

  char* ws = (char*)d_ws;
  const size_t MiB = 1048576;
  u16* nrmT   = (u16*)(ws);                        // 8 MiB  [8][1024][512]
  u16* Qh     = (u16*)(ws + 8 * MiB);              // 8 MiB  [64][1024][64]
  u16* Kfull  = (u16*)(ws + 16 * MiB);             // 9.4 MiB [64][1152][64]
  u16* Vfull  = (u16*)(ws + 26 * MiB);             // 9.4 MiB [64][64][1152]
  u16* attnT  = (u16*)(ws + 36 * MiB);             // 8 MiB  [8][1024][512]
  u16* encT   = (u16*)(ws + 44 * MiB);             // 1 MiB  [8][128][512]
  u16* wQK    = (u16*)(ws + 45 * MiB);             // 1 MiB
  u16* wV     = (u16*)(ws + 46 * MiB);             // 0.5 MiB
  u16* wEK    = (u16*)(ws + 46 * MiB + 524288);
  u16* wEV    = (u16*)(ws + 47 * MiB);
  u16* projwb = (u16*)(ws + 47 * MiB + 524288);
  float* bQK  = (float*)(ws + 48 * MiB);
  float* bV   = (float*)(ws + 48 * MiB + 4096);
  float* bEK  = (float*)(ws + 48 * MiB + 6144);
  float* bEV  = (float*)(ws + 48 * MiB + 8192);

  // 1) fused GroupNorm + prep
  prep_gn_kernel<<<dim3(2305), dim3(256), 0, stream>>>(
      x, nscale, nbias, nrmT, qkv_w, ekv_w, proj_w, enc, qkv_b, ekv_b,
      wQK, wV, wEK, wEV, projwb, encT, bQK, bV, bEK, bEV);

  // 2) Q,K (swapped operands) -> Qh rows, Kfull rows 128..1151
  mfma_gemm<3><<<dim3(8, 8, BB), dim3(256), 0, stream>>>(
      nrmT, wQK, bQK, nullptr, Qh, Kfull, nullptr,
      (long)1024 * 512, 0, 0, 0, 0, 1024, 0, 1152, 128);

  // 3) EK (swapped) -> Kfull rows 0..127
  mfma_gemm<3><<<dim3(4, 1, BB), dim3(256), 0, stream>>>(
      encT, wEK, bEK, nullptr, Kfull, Kfull, nullptr,
      (long)128 * 512, 0, 0, 0, 0, 1152, 0, 1152, 0);

  // 4) V -> Vfull cols 128..1151
  mfma_gemm<0><<<dim3(8, 4, BB), dim3(256), 0, stream>>>(
      wV, nrmT, bV, nullptr, Vfull, nullptr, nullptr,
      0, (long)1024 * 512, 1152, 128, (long)512 * 1152, 0, 0, 0, 0);

  // 5) EV -> Vfull cols 0..127
  mfma_gemm<0><<<dim3(1, 4, BB), dim3(256), 0, stream>>>(
      wEV, encT, bEV, nullptr, Vfull, nullptr, nullptr,
      0, (long)128 * 512, 1152, 0, (long)512 * 1152, 0, 0, 0, 0);

  // 6) attention -> attnT [8][1024][512]
  attn_kernel<<<dim3(64, 8), dim3(256), 0, stream>>>(
      Qh, Kfull, Vfull, mask, attnT);

  // 7) out = x + proj_w @ attn
  mfma_gemm<2><<<dim3(8, 4, BB), dim3(256), 0, stream>>>(
      projwb, attnT, proj_b, x, nullptr, nullptr, out,
      0, (long)1024 * 512, 1024, 0, (long)512 * 1024, 0, 0, 0, 0);
}

// Round 6
// 178.863 us; speedup vs baseline: 74.0315x; 1.1298x over previous
//
#include <hip/hip_runtime.h>
#include <math.h>

#define BB 8
#define TT 1024
#define SS 77

typedef short v8s __attribute__((ext_vector_type(8)));
typedef float v4f __attribute__((ext_vector_type(4)));
typedef unsigned short u16x4 __attribute__((ext_vector_type(4)));
typedef unsigned short u16x8 __attribute__((ext_vector_type(8)));
typedef unsigned short u16;

// fold 64^-0.25 * sqrt(log2 e) into q and k weights -> logits in exp2-domain
#define SCALEF 0.424660891f
#define MASKNEG (-14426.95f)   // -10000 * log2(e)

__device__ __forceinline__ u16 f2bf(float f) {
  unsigned u = __float_as_uint(f);
  u = (u + 0x7fffu + ((u >> 16) & 1u)) >> 16;
  return (u16)u;
}
__device__ __forceinline__ u16 hi16(float f) {
  return (u16)(__float_as_uint(f) >> 16);
}
__device__ __forceinline__ float bf2f(u16 u) {
  return __uint_as_float(((unsigned)u) << 16);
}
__device__ __forceinline__ void gl_lds16(const void* g, void* l) {
  __builtin_amdgcn_global_load_lds(
      (const __attribute__((address_space(1))) void*)g,
      (__attribute__((address_space(3))) void*)l, 16, 0, 0);
}
__device__ __forceinline__ float red16sum(float v) {
  int i;
  i = __builtin_amdgcn_update_dpp(__float_as_int(v), __float_as_int(v), 0xB1, 0xF, 0xF, true);
  v += __int_as_float(i);
  i = __builtin_amdgcn_update_dpp(__float_as_int(v), __float_as_int(v), 0x4E, 0xF, 0xF, true);
  v += __int_as_float(i);
  i = __builtin_amdgcn_ds_swizzle(__float_as_int(v), 0x101F);
  v += __int_as_float(i);
  i = __builtin_amdgcn_update_dpp(__float_as_int(v), __float_as_int(v), 0x128, 0xF, 0xF, true);
  v += __int_as_float(i);
  return v;
}

// ---------------------------------------------------------------------------
// Fused GroupNorm (blocks 0..255) + prep (blocks 256..2304).
// ---------------------------------------------------------------------------
__global__ __launch_bounds__(256) void prep_gn_kernel(
    const float* __restrict__ x, const float* __restrict__ scale,
    const float* __restrict__ bias, u16* __restrict__ nrmT,
    const float* __restrict__ qkv_w, const float* __restrict__ ekv_w,
    const float* __restrict__ proj_w, const float* __restrict__ enc,
    const float* __restrict__ qkv_b, const float* __restrict__ ekv_b,
    u16* __restrict__ wQK, u16* __restrict__ wV, u16* __restrict__ wEK,
    u16* __restrict__ wEV, u16* __restrict__ projwb, u16* __restrict__ encT,
    float* __restrict__ bQK, float* __restrict__ bV,
    float* __restrict__ bEK, float* __restrict__ bEV) {
  __shared__ u16 Xs[16 * 1024];
  __shared__ float red[8];
  int blk = blockIdx.x, tid = threadIdx.x;

  if (blk < 256) {             // ---- GroupNorm path ----
    int bg = blk;
    int b = bg >> 5, g = bg & 31;
    const float4* x4 = (const float4*)(x + (size_t)bg * 16384);
    float s = 0.f, sq = 0.f;
#pragma unroll
    for (int i = 0; i < 16; ++i) {
      int idx = tid + 256 * i;
      float4 v = x4[idx];
      s += v.x + v.y + v.z + v.w;
      sq += v.x * v.x + v.y * v.y + v.z * v.z + v.w * v.w;
      int c = idx >> 8, t4 = (idx & 255) * 4;
      u16x4 o; o.x = f2bf(v.x); o.y = f2bf(v.y); o.z = f2bf(v.z); o.w = f2bf(v.w);
      *(u16x4*)(Xs + c * 1024 + t4) = o;
    }
#pragma unroll
    for (int off = 32; off > 0; off >>= 1) {
      s += __shfl_down(s, off, 64);
      sq += __shfl_down(sq, off, 64);
    }
    int wave = tid >> 6;
    if ((tid & 63) == 0) { red[wave] = s; red[wave + 4] = sq; }
    __syncthreads();
    float ts = red[0] + red[1] + red[2] + red[3];
    float tq = red[4] + red[5] + red[6] + red[7];
    float mu = ts * (1.0f / 16384.0f);
    float var = tq * (1.0f / 16384.0f) - mu * mu;
    float rs = rsqrtf(var + 1e-5f);
    float scv[16], biv[16];
#pragma unroll
    for (int c = 0; c < 16; ++c) {
      float ss = scale[g * 16 + c] * rs;
      scv[c] = ss;
      biv[c] = bias[g * 16 + c] - mu * ss;
    }
#pragma unroll
    for (int j = 0; j < 4; ++j) {
      int t = tid + 256 * j;
      u16x8 o0, o1;
#pragma unroll
      for (int c = 0; c < 8; ++c)  o0[c] = f2bf(bf2f(Xs[c * 1024 + t]) * scv[c] + biv[c]);
#pragma unroll
      for (int c = 8; c < 16; ++c) o1[c - 8] = f2bf(bf2f(Xs[c * 1024 + t]) * scv[c] + biv[c]);
      u16* dst = nrmT + ((size_t)b * 1024 + t) * 512 + g * 16;
      *(u16x8*)dst = o0;
      *(u16x8*)(dst + 8) = o1;
    }
    return;
  }

  int p = blk - 256;           // ---- prep path ----
  if (p < 512) {               // wQK (scaled)
    int idx = p * 256 + tid;
    int n = idx >> 7, c4 = (idx & 127) * 4;
    int which = n >> 9, h = (n >> 6) & 7, ch = n & 63;
    int src = h * 192 + which * 64 + ch;
    float4 v = *(const float4*)(qkv_w + (size_t)src * 512 + c4);
    u16x4 o; o.x = f2bf(v.x * SCALEF); o.y = f2bf(v.y * SCALEF);
    o.z = f2bf(v.z * SCALEF); o.w = f2bf(v.w * SCALEF);
    *(u16x4*)(wQK + (size_t)n * 512 + c4) = o;
  } else if (p < 768) {        // wV
    int idx = (p - 512) * 256 + tid;
    int n = idx >> 7, c4 = (idx & 127) * 4;
    int h = n >> 6, ch = n & 63;
    int src = h * 192 + 128 + ch;
    float4 v = *(const float4*)(qkv_w + (size_t)src * 512 + c4);
    u16x4 o; o.x = f2bf(v.x); o.y = f2bf(v.y); o.z = f2bf(v.z); o.w = f2bf(v.w);
    *(u16x4*)(wV + (size_t)n * 512 + c4) = o;
  } else if (p < 1024) {       // wEK (scaled)
    int idx = (p - 768) * 256 + tid;
    int n = idx >> 7, c4 = (idx & 127) * 4;
    int h = n >> 6, ch = n & 63;
    int src = h * 128 + ch;
    float4 v = *(const float4*)(ekv_w + (size_t)src * 512 + c4);
    u16x4 o; o.x = f2bf(v.x * SCALEF); o.y = f2bf(v.y * SCALEF);
    o.z = f2bf(v.z * SCALEF); o.w = f2bf(v.w * SCALEF);
    *(u16x4*)(wEK + (size_t)n * 512 + c4) = o;
  } else if (p < 1280) {       // wEV
    int idx = (p - 1024) * 256 + tid;
    int n = idx >> 7, c4 = (idx & 127) * 4;
    int h = n >> 6, ch = n & 63;
    int src = h * 128 + 64 + ch;
    float4 v = *(const float4*)(ekv_w + (size_t)src * 512 + c4);
    u16x4 o; o.x = f2bf(v.x); o.y = f2bf(v.y); o.z = f2bf(v.z); o.w = f2bf(v.w);
    *(u16x4*)(wEV + (size_t)n * 512 + c4) = o;
  } else if (p < 1536) {       // projwb
    int idx = (p - 1280) * 256 + tid;
    float4 v = ((const float4*)proj_w)[idx];
    u16x4 o; o.x = f2bf(v.x); o.y = f2bf(v.y); o.z = f2bf(v.z); o.w = f2bf(v.w);
    *(u16x4*)(projwb + (size_t)idx * 4) = o;
  } else if (p < 2048) {       // encT [b][128][512], zero-padded
    int idx = (p - 1536) * 256 + tid;
    int b = idx >> 14, rem = idx & 16383;
    int s = rem >> 7, c = (rem & 127) * 4;
    u16x4 o; o.x = 0; o.y = 0; o.z = 0; o.w = 0;
    if (s < SS) {
      const float* pp = enc + ((size_t)b * 512 + c) * SS + s;
      o.x = f2bf(pp[0]); o.y = f2bf(pp[SS]); o.z = f2bf(pp[2 * SS]); o.w = f2bf(pp[3 * SS]);
    }
    *(u16x4*)(encT + ((size_t)b * 128 + s) * 512 + c) = o;
  } else {                     // biases (permuted; q/k scaled)
    for (int i = tid; i < 2560; i += 256) {
      if (i < 1024) {
        int which = i >> 9, h = (i >> 6) & 7, ch = i & 63;
        bQK[i] = qkv_b[h * 192 + which * 64 + ch] * SCALEF;
      } else if (i < 1536) {
        int j = i - 1024; int h = j >> 6, ch = j & 63;
        bV[j] = qkv_b[h * 192 + 128 + ch];
      } else if (i < 2048) {
        int j = i - 1536; int h = j >> 6, ch = j & 63;
        bEK[j] = ekv_b[h * 128 + ch] * SCALEF;
      } else {
        int j = i - 2048; int h = j >> 6, ch = j & 63;
        bEV[j] = ekv_b[h * 128 + 64 + ch];
      }
    }
  }
}

// ---------------------------------------------------------------------------
// Unified projection GEMM: all four projections (QK, EK, V, EV) in ONE
// launch. grid = (104 jobs, 8 batches). 128x128 tile, BK=64, m97 staging.
//   job  0..63 : QK  (swapped: A=nrmT[t], B=wQK)   -> MODE3 store Qh/Kfull
//   job 64..67 : EK  (swapped: A=encT[s], B=wEK)   -> MODE3 store Kfull
//   job 68..99 : V   (A=wV[o],  B=nrmT[t])         -> MODE0 store Vfull
//   job100..103: EV  (A=wEV[o], B=encT[s])         -> MODE0 store Vfull
// Both epilogues route through LDS for coalesced 16B stores.
// ---------------------------------------------------------------------------
__global__ __launch_bounds__(256) void proj_all(
    const u16* __restrict__ nrmT, const u16* __restrict__ encT,
    const u16* __restrict__ wQK, const u16* __restrict__ wEK,
    const u16* __restrict__ wV, const u16* __restrict__ wEV,
    const float* __restrict__ bQK, const float* __restrict__ bEK,
    const float* __restrict__ bV, const float* __restrict__ bEV,
    u16* __restrict__ Qh, u16* __restrict__ Kfull, u16* __restrict__ Vfull) {
  __shared__ __align__(16) u16 SH[16384];
  u16* As = SH;
  u16* Bs = SH + 8192;

  int job = blockIdx.x, bz = blockIdx.y;
  int tid = threadIdx.x;
  int lane = tid & 63, w = tid >> 6;
  int lan15 = lane & 15, quad = lane >> 4;
  int wm = w >> 1, wn = w & 1;

  int mode, m0, n0;
  const u16 *Ap, *Bp;
  const float* bias;
  u16 *dA = nullptr, *dB = nullptr;
  int TrA = 0, offA = 0, TrB = 0, offB = 0;
  int coff = 0;

  if (job < 64) {
    mode = 3; m0 = (job >> 3) * 128; n0 = (job & 7) * 128;
    Ap = nrmT + (size_t)bz * 1024 * 512; Bp = wQK; bias = bQK;
    dA = Qh; TrA = 1024; offA = 0; dB = Kfull; TrB = 1152; offB = 128;
  } else if (job < 68) {
    mode = 3; m0 = 0; n0 = (job - 64) * 128;
    Ap = encT + (size_t)bz * 128 * 512; Bp = wEK; bias = bEK;
    dA = Kfull; TrA = 1152; offA = 0; dB = Kfull; TrB = 1152; offB = 0;
  } else if (job < 100) {
    int jj = job - 68; mode = 0; m0 = (jj >> 3) * 128; n0 = (jj & 7) * 128;
    Ap = wV; Bp = nrmT + (size_t)bz * 1024 * 512; bias = bV;
    coff = 128;
  } else {
    int jj = job - 100; mode = 0; m0 = jj * 128; n0 = 0;
    Ap = wEV; Bp = encT + (size_t)bz * 128 * 512; bias = bEV;
    coff = 0;
  }

  int srow = lane >> 3;
  int schunk = (lane & 7) ^ srow;
  const char* Ag = (const char*)(Ap + (size_t)(m0 + w * 32 + srow) * 512) + schunk * 16;
  const char* Bg = (const char*)(Bp + (size_t)(n0 + w * 32 + srow) * 512) + schunk * 16;
  char* Al = (char*)As + w * 4096;
  char* Bl = (char*)Bs + w * 4096;

  v4f acc[4][4] = {};

  for (int step = 0; step < 8; ++step) {
    __syncthreads();
    int kb = step * 128;
#pragma unroll
    for (int i = 0; i < 4; ++i) gl_lds16(Ag + kb + i * 8192, Al + i * 1024);
#pragma unroll
    for (int i = 0; i < 4; ++i) gl_lds16(Bg + kb + i * 8192, Bl + i * 1024);
    __syncthreads();

#pragma unroll
    for (int ksub = 0; ksub < 2; ++ksub) {
      int ch = ((ksub * 4 + quad) ^ (lan15 & 7)) * 16;
      v8s a[4], bf[4];
#pragma unroll
      for (int i = 0; i < 4; ++i)
        a[i] = *(const v8s*)((const char*)As + (wm * 64 + i * 16 + lan15) * 128 + ch);
#pragma unroll
      for (int j = 0; j < 4; ++j)
        bf[j] = *(const v8s*)((const char*)Bs + (wn * 64 + j * 16 + lan15) * 128 + ch);
#pragma unroll
      for (int i = 0; i < 4; ++i)
#pragma unroll
        for (int j = 0; j < 4; ++j)
          acc[i][j] = __builtin_amdgcn_mfma_f32_16x16x32_bf16(a[i], bf[j], acc[i][j], 0, 0, 0);
    }
  }

  if (mode == 3) {
    // transposed head-major store: D[t][n] -> dst[((bz*8+h)*Trows+off+t)*64+ch]
    u16* Tr = SH;              // [128][72]
    for (int ph = 0; ph < 2; ++ph) {
      __syncthreads();
      if (wn == ph) {
#pragma unroll
        for (int j = 0; j < 4; ++j) {
          int n = n0 + wn * 64 + j * 16 + lan15;
          float bv_ = bias[n];
#pragma unroll
          for (int i = 0; i < 4; ++i)
#pragma unroll
            for (int r = 0; r < 4; ++r)
              Tr[(wm * 64 + i * 16 + quad * 4 + r) * 72 + j * 16 + lan15] =
                  f2bf(acc[i][j][r] + bv_);
        }
      }
      __syncthreads();
      int nb = n0 + ph * 64;
      u16* dst = (nb < 512) ? dA : dB;
      int Trows = (nb < 512) ? TrA : TrB;
      int roff  = (nb < 512) ? offA : offB;
      int hh = (nb & 511) >> 6;
      int row = tid >> 1, seg = (tid & 1) * 32;
      u16* dp = dst + ((size_t)(bz * 8 + hh) * Trows + roff + m0 + row) * 64 + seg;
#pragma unroll
      for (int g = 0; g < 4; ++g)
        *(u16x8*)(dp + g * 8) = *(const u16x8*)(Tr + row * 72 + seg + g * 8);
    }
  } else {
    // direct store D[o][n] via LDS for coalescing: Vfull[bz][o][coff+n]
    u16* Tr = SH;              // [128 m][72] per phase of 64 n
    u16* Cb = Vfull + (size_t)bz * 512 * 1152;
    for (int ph = 0; ph < 2; ++ph) {
      __syncthreads();
      if (wn == ph) {
#pragma unroll
        for (int i = 0; i < 4; ++i) {
          int ob = wm * 64 + i * 16 + quad * 4;
#pragma unroll
          for (int r = 0; r < 4; ++r) {
            float bi = bias[m0 + ob + r];
#pragma unroll
            for (int j = 0; j < 4; ++j)
              Tr[(ob + r) * 72 + j * 16 + lan15] = f2bf(acc[i][j][r] + bi);
          }
        }
      }
      __syncthreads();
      int row = tid >> 1, seg = (tid & 1) * 32;
      u16* dp = Cb + (size_t)(m0 + row) * 1152 + coff + n0 + ph * 64 + seg;
#pragma unroll
      for (int g = 0; g < 4; ++g)
        *(u16x8*)(dp + g * 8) = *(const u16x8*)(Tr + row * 72 + seg + g * 8);
    }
  }
}

// ---------------------------------------------------------------------------
// proj-out GEMM: out = x + proj_w @ attn.  A=projwb [512][512],
// B=attnT [bz][1024 t][512]. fp32 out + residual. grid (8,4,8).
// ---------------------------------------------------------------------------
__global__ __launch_bounds__(256) void proj_out(
    const u16* __restrict__ A, const u16* __restrict__ B,
    const float* __restrict__ bias, const float* __restrict__ res,
    float* __restrict__ Cf) {
  __shared__ __align__(16) u16 SH[16384];
  u16* As = SH;
  u16* Bs = SH + 8192;

  int tid = threadIdx.x;
  int lane = tid & 63, w = tid >> 6;
  int lan15 = lane & 15, quad = lane >> 4;
  int wm = w >> 1, wn = w & 1;
  int m0 = blockIdx.y * 128, n0 = blockIdx.x * 128;
  int bz = blockIdx.z;
  const u16* Bb = B + (size_t)bz * 1024 * 512;

  int srow = lane >> 3;
  int schunk = (lane & 7) ^ srow;
  const char* Ag = (const char*)(A + (size_t)(m0 + w * 32 + srow) * 512) + schunk * 16;
  const char* Bg = (const char*)(Bb + (size_t)(n0 + w * 32 + srow) * 512) + schunk * 16;
  char* Al = (char*)As + w * 4096;
  char* Bl = (char*)Bs + w * 4096;

  v4f acc[4][4] = {};

  for (int step = 0; step < 8; ++step) {
    __syncthreads();
    int kb = step * 128;
#pragma unroll
    for (int i = 0; i < 4; ++i) gl_lds16(Ag + kb + i * 8192, Al + i * 1024);
#pragma unroll
    for (int i = 0; i < 4; ++i) gl_lds16(Bg + kb + i * 8192, Bl + i * 1024);
    __syncthreads();

#pragma unroll
    for (int ksub = 0; ksub < 2; ++ksub) {
      int ch = ((ksub * 4 + quad) ^ (lan15 & 7)) * 16;
      v8s a[4], bf[4];
#pragma unroll
      for (int i = 0; i < 4; ++i)
        a[i] = *(const v8s*)((const char*)As + (wm * 64 + i * 16 + lan15) * 128 + ch);
#pragma unroll
      for (int j = 0; j < 4; ++j)
        bf[j] = *(const v8s*)((const char*)Bs + (wn * 64 + j * 16 + lan15) * 128 + ch);
#pragma unroll
      for (int i = 0; i < 4; ++i)
#pragma unroll
        for (int j = 0; j < 4; ++j)
          acc[i][j] = __builtin_amdgcn_mfma_f32_16x16x32_bf16(a[i], bf[j], acc[i][j], 0, 0, 0);
    }
  }

  const float* rb = res + (size_t)bz * 512 * 1024;
  float* Cb = Cf + (size_t)bz * 512 * 1024;
#pragma unroll
  for (int i = 0; i < 4; ++i) {
    int ob = m0 + wm * 64 + i * 16 + quad * 4;
#pragma unroll
    for (int r = 0; r < 4; ++r) {
      int o = ob + r;
      float bi = bias[o];
#pragma unroll
      for (int j = 0; j < 4; ++j) {
        int n = n0 + wn * 64 + j * 16 + lan15;
        Cb[(size_t)o * 1024 + n] = acc[i][j][r] + bi + rb[(size_t)o * 1024 + n];
      }
    }
  }
}

// ---------------------------------------------------------------------------
// MFMA flash attention v3: fixed-max exp2 softmax, K/V double-buffer,
// 1 barrier/chunk. Block = 4 waves x 32 t = 128 t; grid (64 bh, 8).
// ---------------------------------------------------------------------------
#define AOFF_K 0           // 2 x 8192
#define AOFF_V 16384       // 2 x 8192
#define AOFF_P 32768       // 4 waves x 4608 (Q overlay + P)
#define AOFF_AM 51200
#define ASMEM  51712

__global__ __launch_bounds__(256) void attn_kernel(
    const u16* __restrict__ Qh, const u16* __restrict__ Kf,
    const u16* __restrict__ Vf, const int* __restrict__ mask,
    u16* __restrict__ attnT) {
  __shared__ __align__(16) unsigned char smem[ASMEM];
  float* AM = (float*)(smem + AOFF_AM);

  int bh = blockIdx.x, b = bh >> 3, h = bh & 7;
  int t0 = blockIdx.y * 128;
  int tid = threadIdx.x;
  int lane = tid & 63, w = tid >> 6;
  int lan15 = lane & 15, quad = lane >> 4;
  int r8 = lane >> 3, c8 = lane & 7;
  int swE = (c8 ^ r8) * 8;

  const u16* Qb = Qh + (size_t)bh * 1024 * 64;
  const u16* Kb = Kf + (size_t)bh * 1152 * 64;
  const u16* Vb = Vf + (size_t)bh * 64 * 1152;
  char* Pw = (char*)smem + AOFF_P + w * 4608;

  if (tid < 128)
    AM[tid] = (tid < SS) ? ((mask[h * SS + tid] != 0) ? 0.f : MASKNEG) : -1e30f;

#pragma unroll
  for (int i = 0; i < 4; ++i)
    gl_lds16(Qb + (size_t)(t0 + w * 32 + i * 8 + r8) * 64 + swE, Pw + i * 1024);
#pragma unroll
  for (int i = 0; i < 2; ++i) {
    int row = w * 16 + i * 8;
    gl_lds16(Kb + (size_t)(row + r8) * 64 + swE, (char*)smem + AOFF_K + row * 128);
    gl_lds16(Vb + (size_t)(row + r8) * 1152 + swE, (char*)smem + AOFF_V + row * 128);
  }
  __syncthreads();

  v8s aq[2][2];
#pragma unroll
  for (int mt = 0; mt < 2; ++mt)
#pragma unroll
    for (int ks = 0; ks < 2; ++ks)
      aq[mt][ks] = *(const v8s*)(Pw + (mt * 16 + lan15) * 128 +
                                 (((ks * 4 + quad) ^ (lan15 & 7)) * 16));

  v4f O[2][4] = {};
  float lsum[2][4] = {};

  for (int c = 0; c < 18; ++c) {
    int cur = c & 1;
    if (c < 17) {
      int nb = cur ^ 1;
#pragma unroll
      for (int i = 0; i < 2; ++i) {
        int row = w * 16 + i * 8;
        gl_lds16(Kb + (size_t)((c + 1) * 64 + row + r8) * 64 + swE,
                 (char*)smem + AOFF_K + nb * 8192 + row * 128);
        gl_lds16(Vb + (size_t)(row + r8) * 1152 + (c + 1) * 64 + swE,
                 (char*)smem + AOFF_V + nb * 8192 + row * 128);
      }
    }
    const char* Kc = (const char*)smem + AOFF_K + cur * 8192;
    const char* Vc = (const char*)smem + AOFF_V + cur * 8192;

    v4f S[2][4] = {};
#pragma unroll
    for (int ks = 0; ks < 2; ++ks) {
      int cofs = ((ks * 4 + quad) ^ (lan15 & 7)) * 16;
      v8s bk[4];
#pragma unroll
      for (int nt = 0; nt < 4; ++nt)
        bk[nt] = *(const v8s*)(Kc + (nt * 16 + lan15) * 128 + cofs);
#pragma unroll
      for (int mt = 0; mt < 2; ++mt)
#pragma unroll
        for (int nt = 0; nt < 4; ++nt)
          S[mt][nt] = __builtin_amdgcn_mfma_f32_16x16x32_bf16(aq[mt][ks], bk[nt], S[mt][nt], 0, 0, 0);
    }

    float add_[4] = {0.f, 0.f, 0.f, 0.f};
    if (c < 2) {
#pragma unroll
      for (int nt = 0; nt < 4; ++nt) add_[nt] = AM[c * 64 + nt * 16 + lan15];
    }
    u16* Pu = (u16*)Pw;
#pragma unroll
    for (int mt = 0; mt < 2; ++mt)
#pragma unroll
      for (int r = 0; r < 4; ++r) {
        float e0 = __builtin_amdgcn_exp2f(S[mt][0][r] + add_[0]);
        float e1 = __builtin_amdgcn_exp2f(S[mt][1][r] + add_[1]);
        float e2 = __builtin_amdgcn_exp2f(S[mt][2][r] + add_[2]);
        float e3 = __builtin_amdgcn_exp2f(S[mt][3][r] + add_[3]);
        int rw = (mt * 16 + quad * 4 + r) * 72 + lan15;
        Pu[rw] = hi16(e0); Pu[rw + 16] = hi16(e1);
        Pu[rw + 32] = hi16(e2); Pu[rw + 48] = hi16(e3);
        lsum[mt][r] += (e0 + e1) + (e2 + e3);
      }

#pragma unroll
    for (int ks = 0; ks < 2; ++ks) {
      int cofs = ((ks * 4 + quad) ^ (lan15 & 7)) * 16;
      v8s ap[2], bv[4];
#pragma unroll
      for (int mt = 0; mt < 2; ++mt)
        ap[mt] = *(const v8s*)(Pw + (mt * 16 + lan15) * 144 + ks * 64 + quad * 16);
#pragma unroll
      for (int nc = 0; nc < 4; ++nc)
        bv[nc] = *(const v8s*)(Vc + (nc * 16 + lan15) * 128 + cofs);
#pragma unroll
      for (int mt = 0; mt < 2; ++mt)
#pragma unroll
        for (int nc = 0; nc < 4; ++nc)
          O[mt][nc] = __builtin_amdgcn_mfma_f32_16x16x32_bf16(ap[mt], bv[nc], O[mt][nc], 0, 0, 0);
    }
    __syncthreads();
  }

  float inv[2][4];
#pragma unroll
  for (int mt = 0; mt < 2; ++mt)
#pragma unroll
    for (int r = 0; r < 4; ++r) inv[mt][r] = 1.0f / red16sum(lsum[mt][r]);

  float* Ot = (float*)smem;
#pragma unroll
  for (int mt = 0; mt < 2; ++mt)
#pragma unroll
    for (int nc = 0; nc < 4; ++nc)
#pragma unroll
      for (int r = 0; r < 4; ++r)
        Ot[(w * 32 + mt * 16 + quad * 4 + r) * 68 + nc * 16 + lan15] =
            O[mt][nc][r] * inv[mt][r];
  __syncthreads();
  {
    int row = tid >> 1, seg = (tid & 1) * 32;
    const float* src = Ot + row * 68 + seg;
    u16* dp = attnT + ((size_t)b * 1024 + t0 + row) * 512 + h * 64 + seg;
#pragma unroll
    for (int g = 0; g < 4; ++g) {
      u16x8 o;
#pragma unroll
      for (int k = 0; k < 8; ++k) o[k] = f2bf(src[g * 8 + k]);
      *(u16x8*)(dp + g * 8) = o;
    }
  }
}

// ---------------------------------------------------------------------------
extern "C" void kernel_launch(void* const* d_in, const int* in_sizes, int n_in,
                              void* d_out, int out_size, void* d_ws, size_t ws_size,
                              hipStream_t stream) {
  const float* x       = (const float*)d_in[0];
  const float* enc     = (const float*)d_in[1];
  const int*   mask    = (const int*)d_in[2];
  const float* nscale  = (const float*)d_in[3];
  const float* nbias   = (const float*)d_in[4];
  const float* qkv_w   = (const float*)d_in[5];
  const float* qkv_b   = (const float*)d_in[6];
  const float* ekv_w   = (const float*)d_in[7];
  const float* ekv_b   = (const float*)d_in[8];
  const float* proj_w  = (const float*)d_in[9];
  const float* proj_b  = (const float*)d_in[10];
  float* out = (float*)d_out;

  char* ws = (char*)d_ws;
  const size_t MiB = 1048576;
  u16* nrmT   = (u16*)(ws);                        // 8 MiB  [8][1024][512]
  u16* Qh     = (u16*)(ws + 8 * MiB);              // 8 MiB  [64][1024][64]
  u16* Kfull  = (u16*)(ws + 16 * MiB);             // 9.4 MiB [64][1152][64]
  u16* Vfull  = (u16*)(ws + 26 * MiB);             // 9.4 MiB [64][64][1152]
  u16* attnT  = (u16*)(ws + 36 * MiB);             // 8 MiB  [8][1024][512]
  u16* encT   = (u16*)(ws + 44 * MiB);             // 1 MiB  [8][128][512]
  u16* wQK    = (u16*)(ws + 45 * MiB);             // 1 MiB
  u16* wV     = (u16*)(ws + 46 * MiB);             // 0.5 MiB
  u16* wEK    = (u16*)(ws + 46 * MiB + 524288);
  u16* wEV    = (u16*)(ws + 47 * MiB);
  u16* projwb = (u16*)(ws + 47 * MiB + 524288);
  float* bQK  = (float*)(ws + 48 * MiB);
  float* bV   = (float*)(ws + 48 * MiB + 4096);
  float* bEK  = (float*)(ws + 48 * MiB + 6144);
  float* bEV  = (float*)(ws + 48 * MiB + 8192);

  // 1) fused GroupNorm + prep
  prep_gn_kernel<<<dim3(2305), dim3(256), 0, stream>>>(
      x, nscale, nbias, nrmT, qkv_w, ekv_w, proj_w, enc, qkv_b, ekv_b,
      wQK, wV, wEK, wEV, projwb, encT, bQK, bV, bEK, bEV);

  // 2) ALL projections (QK + EK + V + EV) in one launch
  proj_all<<<dim3(104, BB), dim3(256), 0, stream>>>(
      nrmT, encT, wQK, wEK, wV, wEV, bQK, bEK, bV, bEV, Qh, Kfull, Vfull);

  // 3) attention -> attnT [8][1024][512]
  attn_kernel<<<dim3(64, 8), dim3(256), 0, stream>>>(
      Qh, Kfull, Vfull, mask, attnT);

  // 4) out = x + proj_w @ attn
  proj_out<<<dim3(8, 4, BB), dim3(256), 0, stream>>>(
      projwb, attnT, proj_b, x, out);
}

// Round 7
// 174.842 us; speedup vs baseline: 75.7342x; 1.0230x over previous
//
#include <hip/hip_runtime.h>
#include <math.h>

#define BB 8
#define TT 1024
#define SS 77

typedef short v8s __attribute__((ext_vector_type(8)));
typedef float v4f __attribute__((ext_vector_type(4)));
typedef unsigned short u16x4 __attribute__((ext_vector_type(4)));
typedef unsigned short u16x8 __attribute__((ext_vector_type(8)));
typedef unsigned short u16;

// fold 64^-0.25 * sqrt(log2 e) into q and k weights -> logits in exp2-domain
#define SCALEF 0.424660891f
#define MASKNEG (-14426.95f)   // -10000 * log2(e)

__device__ __forceinline__ u16 f2bf(float f) {
  unsigned u = __float_as_uint(f);
  u = (u + 0x7fffu + ((u >> 16) & 1u)) >> 16;
  return (u16)u;
}
__device__ __forceinline__ u16 hi16(float f) {
  return (u16)(__float_as_uint(f) >> 16);
}
__device__ __forceinline__ float bf2f(u16 u) {
  return __uint_as_float(((unsigned)u) << 16);
}
__device__ __forceinline__ void gl_lds16(const void* g, void* l) {
  __builtin_amdgcn_global_load_lds(
      (const __attribute__((address_space(1))) void*)g,
      (__attribute__((address_space(3))) void*)l, 16, 0, 0);
}

// ---------------------------------------------------------------------------
// Fused GroupNorm (blocks 0..255) + prep (blocks 256..2304).
// ---------------------------------------------------------------------------
__global__ __launch_bounds__(256) void prep_gn_kernel(
    const float* __restrict__ x, const float* __restrict__ scale,
    const float* __restrict__ bias, u16* __restrict__ nrmT,
    const float* __restrict__ qkv_w, const float* __restrict__ ekv_w,
    const float* __restrict__ proj_w, const float* __restrict__ enc,
    const float* __restrict__ qkv_b, const float* __restrict__ ekv_b,
    u16* __restrict__ wQK, u16* __restrict__ wV, u16* __restrict__ wEK,
    u16* __restrict__ wEV, u16* __restrict__ projwb, u16* __restrict__ encT,
    float* __restrict__ bQK, float* __restrict__ bV,
    float* __restrict__ bEK, float* __restrict__ bEV) {
  __shared__ u16 Xs[16 * 1024];
  __shared__ float red[8];
  int blk = blockIdx.x, tid = threadIdx.x;

  if (blk < 256) {             // ---- GroupNorm path ----
    int bg = blk;
    int b = bg >> 5, g = bg & 31;
    const float4* x4 = (const float4*)(x + (size_t)bg * 16384);
    float s = 0.f, sq = 0.f;
#pragma unroll
    for (int i = 0; i < 16; ++i) {
      int idx = tid + 256 * i;
      float4 v = x4[idx];
      s += v.x + v.y + v.z + v.w;
      sq += v.x * v.x + v.y * v.y + v.z * v.z + v.w * v.w;
      int c = idx >> 8, t4 = (idx & 255) * 4;
      u16x4 o; o.x = f2bf(v.x); o.y = f2bf(v.y); o.z = f2bf(v.z); o.w = f2bf(v.w);
      *(u16x4*)(Xs + c * 1024 + t4) = o;
    }
#pragma unroll
    for (int off = 32; off > 0; off >>= 1) {
      s += __shfl_down(s, off, 64);
      sq += __shfl_down(sq, off, 64);
    }
    int wave = tid >> 6;
    if ((tid & 63) == 0) { red[wave] = s; red[wave + 4] = sq; }
    __syncthreads();
    float ts = red[0] + red[1] + red[2] + red[3];
    float tq = red[4] + red[5] + red[6] + red[7];
    float mu = ts * (1.0f / 16384.0f);
    float var = tq * (1.0f / 16384.0f) - mu * mu;
    float rs = rsqrtf(var + 1e-5f);
    float scv[16], biv[16];
#pragma unroll
    for (int c = 0; c < 16; ++c) {
      float ss = scale[g * 16 + c] * rs;
      scv[c] = ss;
      biv[c] = bias[g * 16 + c] - mu * ss;
    }
#pragma unroll
    for (int j = 0; j < 4; ++j) {
      int t = tid + 256 * j;
      u16x8 o0, o1;
#pragma unroll
      for (int c = 0; c < 8; ++c)  o0[c] = f2bf(bf2f(Xs[c * 1024 + t]) * scv[c] + biv[c]);
#pragma unroll
      for (int c = 8; c < 16; ++c) o1[c - 8] = f2bf(bf2f(Xs[c * 1024 + t]) * scv[c] + biv[c]);
      u16* dst = nrmT + ((size_t)b * 1024 + t) * 512 + g * 16;
      *(u16x8*)dst = o0;
      *(u16x8*)(dst + 8) = o1;
    }
    return;
  }

  int p = blk - 256;           // ---- prep path ----
  if (p < 512) {               // wQK (scaled)
    int idx = p * 256 + tid;
    int n = idx >> 7, c4 = (idx & 127) * 4;
    int which = n >> 9, h = (n >> 6) & 7, ch = n & 63;
    int src = h * 192 + which * 64 + ch;
    float4 v = *(const float4*)(qkv_w + (size_t)src * 512 + c4);
    u16x4 o; o.x = f2bf(v.x * SCALEF); o.y = f2bf(v.y * SCALEF);
    o.z = f2bf(v.z * SCALEF); o.w = f2bf(v.w * SCALEF);
    *(u16x4*)(wQK + (size_t)n * 512 + c4) = o;
  } else if (p < 768) {        // wV
    int idx = (p - 512) * 256 + tid;
    int n = idx >> 7, c4 = (idx & 127) * 4;
    int h = n >> 6, ch = n & 63;
    int src = h * 192 + 128 + ch;
    float4 v = *(const float4*)(qkv_w + (size_t)src * 512 + c4);
    u16x4 o; o.x = f2bf(v.x); o.y = f2bf(v.y); o.z = f2bf(v.z); o.w = f2bf(v.w);
    *(u16x4*)(wV + (size_t)n * 512 + c4) = o;
  } else if (p < 1024) {       // wEK (scaled)
    int idx = (p - 768) * 256 + tid;
    int n = idx >> 7, c4 = (idx & 127) * 4;
    int h = n >> 6, ch = n & 63;
    int src = h * 128 + ch;
    float4 v = *(const float4*)(ekv_w + (size_t)src * 512 + c4);
    u16x4 o; o.x = f2bf(v.x * SCALEF); o.y = f2bf(v.y * SCALEF);
    o.z = f2bf(v.z * SCALEF); o.w = f2bf(v.w * SCALEF);
    *(u16x4*)(wEK + (size_t)n * 512 + c4) = o;
  } else if (p < 1280) {       // wEV
    int idx = (p - 1024) * 256 + tid;
    int n = idx >> 7, c4 = (idx & 127) * 4;
    int h = n >> 6, ch = n & 63;
    int src = h * 128 + 64 + ch;
    float4 v = *(const float4*)(ekv_w + (size_t)src * 512 + c4);
    u16x4 o; o.x = f2bf(v.x); o.y = f2bf(v.y); o.z = f2bf(v.z); o.w = f2bf(v.w);
    *(u16x4*)(wEV + (size_t)n * 512 + c4) = o;
  } else if (p < 1536) {       // projwb
    int idx = (p - 1280) * 256 + tid;
    float4 v = ((const float4*)proj_w)[idx];
    u16x4 o; o.x = f2bf(v.x); o.y = f2bf(v.y); o.z = f2bf(v.z); o.w = f2bf(v.w);
    *(u16x4*)(projwb + (size_t)idx * 4) = o;
  } else if (p < 2048) {       // encT [b][128][512], zero-padded
    int idx = (p - 1536) * 256 + tid;
    int b = idx >> 14, rem = idx & 16383;
    int s = rem >> 7, c = (rem & 127) * 4;
    u16x4 o; o.x = 0; o.y = 0; o.z = 0; o.w = 0;
    if (s < SS) {
      const float* pp = enc + ((size_t)b * 512 + c) * SS + s;
      o.x = f2bf(pp[0]); o.y = f2bf(pp[SS]); o.z = f2bf(pp[2 * SS]); o.w = f2bf(pp[3 * SS]);
    }
    *(u16x4*)(encT + ((size_t)b * 128 + s) * 512 + c) = o;
  } else {                     // biases (permuted; q/k scaled)
    for (int i = tid; i < 2560; i += 256) {
      if (i < 1024) {
        int which = i >> 9, h = (i >> 6) & 7, ch = i & 63;
        bQK[i] = qkv_b[h * 192 + which * 64 + ch] * SCALEF;
      } else if (i < 1536) {
        int j = i - 1024; int h = j >> 6, ch = j & 63;
        bV[j] = qkv_b[h * 192 + 128 + ch];
      } else if (i < 2048) {
        int j = i - 1536; int h = j >> 6, ch = j & 63;
        bEK[j] = ekv_b[h * 128 + ch] * SCALEF;
      } else {
        int j = i - 2048; int h = j >> 6, ch = j & 63;
        bEV[j] = ekv_b[h * 128 + 64 + ch];
      }
    }
  }
}

// ---------------------------------------------------------------------------
// Unified projection GEMM: all four projections (QK, EK, V, EV) in ONE
// launch. grid = (104 jobs, 8 batches). 128x128 tile, BK=64, m97 staging.
// ---------------------------------------------------------------------------
__global__ __launch_bounds__(256) void proj_all(
    const u16* __restrict__ nrmT, const u16* __restrict__ encT,
    const u16* __restrict__ wQK, const u16* __restrict__ wEK,
    const u16* __restrict__ wV, const u16* __restrict__ wEV,
    const float* __restrict__ bQK, const float* __restrict__ bEK,
    const float* __restrict__ bV, const float* __restrict__ bEV,
    u16* __restrict__ Qh, u16* __restrict__ Kfull, u16* __restrict__ Vfull) {
  __shared__ __align__(16) u16 SH[16384];
  u16* As = SH;
  u16* Bs = SH + 8192;

  int job = blockIdx.x, bz = blockIdx.y;
  int tid = threadIdx.x;
  int lane = tid & 63, w = tid >> 6;
  int lan15 = lane & 15, quad = lane >> 4;
  int wm = w >> 1, wn = w & 1;

  int mode, m0, n0;
  const u16 *Ap, *Bp;
  const float* bias;
  u16 *dA = nullptr, *dB = nullptr;
  int TrA = 0, offA = 0, TrB = 0, offB = 0;
  int coff = 0;

  if (job < 64) {
    mode = 3; m0 = (job >> 3) * 128; n0 = (job & 7) * 128;
    Ap = nrmT + (size_t)bz * 1024 * 512; Bp = wQK; bias = bQK;
    dA = Qh; TrA = 1024; offA = 0; dB = Kfull; TrB = 1152; offB = 128;
  } else if (job < 68) {
    mode = 3; m0 = 0; n0 = (job - 64) * 128;
    Ap = encT + (size_t)bz * 128 * 512; Bp = wEK; bias = bEK;
    dA = Kfull; TrA = 1152; offA = 0; dB = Kfull; TrB = 1152; offB = 0;
  } else if (job < 100) {
    int jj = job - 68; mode = 0; m0 = (jj >> 3) * 128; n0 = (jj & 7) * 128;
    Ap = wV; Bp = nrmT + (size_t)bz * 1024 * 512; bias = bV;
    coff = 128;
  } else {
    int jj = job - 100; mode = 0; m0 = jj * 128; n0 = 0;
    Ap = wEV; Bp = encT + (size_t)bz * 128 * 512; bias = bEV;
    coff = 0;
  }

  int srow = lane >> 3;
  int schunk = (lane & 7) ^ srow;
  const char* Ag = (const char*)(Ap + (size_t)(m0 + w * 32 + srow) * 512) + schunk * 16;
  const char* Bg = (const char*)(Bp + (size_t)(n0 + w * 32 + srow) * 512) + schunk * 16;
  char* Al = (char*)As + w * 4096;
  char* Bl = (char*)Bs + w * 4096;

  v4f acc[4][4] = {};

  for (int step = 0; step < 8; ++step) {
    __syncthreads();
    int kb = step * 128;
#pragma unroll
    for (int i = 0; i < 4; ++i) gl_lds16(Ag + kb + i * 8192, Al + i * 1024);
#pragma unroll
    for (int i = 0; i < 4; ++i) gl_lds16(Bg + kb + i * 8192, Bl + i * 1024);
    __syncthreads();

#pragma unroll
    for (int ksub = 0; ksub < 2; ++ksub) {
      int ch = ((ksub * 4 + quad) ^ (lan15 & 7)) * 16;
      v8s a[4], bf[4];
#pragma unroll
      for (int i = 0; i < 4; ++i)
        a[i] = *(const v8s*)((const char*)As + (wm * 64 + i * 16 + lan15) * 128 + ch);
#pragma unroll
      for (int j = 0; j < 4; ++j)
        bf[j] = *(const v8s*)((const char*)Bs + (wn * 64 + j * 16 + lan15) * 128 + ch);
#pragma unroll
      for (int i = 0; i < 4; ++i)
#pragma unroll
        for (int j = 0; j < 4; ++j)
          acc[i][j] = __builtin_amdgcn_mfma_f32_16x16x32_bf16(a[i], bf[j], acc[i][j], 0, 0, 0);
    }
  }

  if (mode == 3) {
    u16* Tr = SH;              // [128][72]
    for (int ph = 0; ph < 2; ++ph) {
      __syncthreads();
      if (wn == ph) {
#pragma unroll
        for (int j = 0; j < 4; ++j) {
          int n = n0 + wn * 64 + j * 16 + lan15;
          float bv_ = bias[n];
#pragma unroll
          for (int i = 0; i < 4; ++i)
#pragma unroll
            for (int r = 0; r < 4; ++r)
              Tr[(wm * 64 + i * 16 + quad * 4 + r) * 72 + j * 16 + lan15] =
                  f2bf(acc[i][j][r] + bv_);
        }
      }
      __syncthreads();
      int nb = n0 + ph * 64;
      u16* dst = (nb < 512) ? dA : dB;
      int Trows = (nb < 512) ? TrA : TrB;
      int roff  = (nb < 512) ? offA : offB;
      int hh = (nb & 511) >> 6;
      int row = tid >> 1, seg = (tid & 1) * 32;
      u16* dp = dst + ((size_t)(bz * 8 + hh) * Trows + roff + m0 + row) * 64 + seg;
#pragma unroll
      for (int g = 0; g < 4; ++g)
        *(u16x8*)(dp + g * 8) = *(const u16x8*)(Tr + row * 72 + seg + g * 8);
    }
  } else {
    u16* Tr = SH;              // [128 m][72] per phase of 64 n
    u16* Cb = Vfull + (size_t)bz * 512 * 1152;
    for (int ph = 0; ph < 2; ++ph) {
      __syncthreads();
      if (wn == ph) {
#pragma unroll
        for (int i = 0; i < 4; ++i) {
          int ob = wm * 64 + i * 16 + quad * 4;
#pragma unroll
          for (int r = 0; r < 4; ++r) {
            float bi = bias[m0 + ob + r];
#pragma unroll
            for (int j = 0; j < 4; ++j)
              Tr[(ob + r) * 72 + j * 16 + lan15] = f2bf(acc[i][j][r] + bi);
          }
        }
      }
      __syncthreads();
      int row = tid >> 1, seg = (tid & 1) * 32;
      u16* dp = Cb + (size_t)(m0 + row) * 1152 + coff + n0 + ph * 64 + seg;
#pragma unroll
      for (int g = 0; g < 4; ++g)
        *(u16x8*)(dp + g * 8) = *(const u16x8*)(Tr + row * 72 + seg + g * 8);
    }
  }
}

// ---------------------------------------------------------------------------
// proj-out GEMM: out = x + proj_w @ attn.
// ---------------------------------------------------------------------------
__global__ __launch_bounds__(256) void proj_out(
    const u16* __restrict__ A, const u16* __restrict__ B,
    const float* __restrict__ bias, const float* __restrict__ res,
    float* __restrict__ Cf) {
  __shared__ __align__(16) u16 SH[16384];
  u16* As = SH;
  u16* Bs = SH + 8192;

  int tid = threadIdx.x;
  int lane = tid & 63, w = tid >> 6;
  int lan15 = lane & 15, quad = lane >> 4;
  int wm = w >> 1, wn = w & 1;
  int m0 = blockIdx.y * 128, n0 = blockIdx.x * 128;
  int bz = blockIdx.z;
  const u16* Bb = B + (size_t)bz * 1024 * 512;

  int srow = lane >> 3;
  int schunk = (lane & 7) ^ srow;
  const char* Ag = (const char*)(A + (size_t)(m0 + w * 32 + srow) * 512) + schunk * 16;
  const char* Bg = (const char*)(Bb + (size_t)(n0 + w * 32 + srow) * 512) + schunk * 16;
  char* Al = (char*)As + w * 4096;
  char* Bl = (char*)Bs + w * 4096;

  v4f acc[4][4] = {};

  for (int step = 0; step < 8; ++step) {
    __syncthreads();
    int kb = step * 128;
#pragma unroll
    for (int i = 0; i < 4; ++i) gl_lds16(Ag + kb + i * 8192, Al + i * 1024);
#pragma unroll
    for (int i = 0; i < 4; ++i) gl_lds16(Bg + kb + i * 8192, Bl + i * 1024);
    __syncthreads();

#pragma unroll
    for (int ksub = 0; ksub < 2; ++ksub) {
      int ch = ((ksub * 4 + quad) ^ (lan15 & 7)) * 16;
      v8s a[4], bf[4];
#pragma unroll
      for (int i = 0; i < 4; ++i)
        a[i] = *(const v8s*)((const char*)As + (wm * 64 + i * 16 + lan15) * 128 + ch);
#pragma unroll
      for (int j = 0; j < 4; ++j)
        bf[j] = *(const v8s*)((const char*)Bs + (wn * 64 + j * 16 + lan15) * 128 + ch);
#pragma unroll
      for (int i = 0; i < 4; ++i)
#pragma unroll
        for (int j = 0; j < 4; ++j)
          acc[i][j] = __builtin_amdgcn_mfma_f32_16x16x32_bf16(a[i], bf[j], acc[i][j], 0, 0, 0);
    }
  }

  const float* rb = res + (size_t)bz * 512 * 1024;
  float* Cb = Cf + (size_t)bz * 512 * 1024;
#pragma unroll
  for (int i = 0; i < 4; ++i) {
    int ob = m0 + wm * 64 + i * 16 + quad * 4;
#pragma unroll
    for (int r = 0; r < 4; ++r) {
      int o = ob + r;
      float bi = bias[o];
#pragma unroll
      for (int j = 0; j < 4; ++j) {
        int n = n0 + wn * 64 + j * 16 + lan15;
        Cb[(size_t)o * 1024 + n] = acc[i][j][r] + bi + rb[(size_t)o * 1024 + n];
      }
    }
  }
}

// ---------------------------------------------------------------------------
// MFMA flash attention v4: S^T-form QK (swapped MFMA operands) so each lane
// holds 4 s-contiguous P values -> b64-packed P stores (8 instead of 32 LDS
// writes per wave-chunk). Fixed-max exp2 softmax; per-lane scalar l (all 16
// lane values share one t); l transposed once at end via LDS bounce.
// Block = 4 waves x 32 t; grid (64 bh, 8). K/V double-buffered, 1 barrier.
// ---------------------------------------------------------------------------
#define AOFF_K 0           // 2 x 8192
#define AOFF_V 16384       // 2 x 8192
#define AOFF_P 32768       // 4 waves x 4608 (Q overlay + P [32][72])
#define AOFF_AM 51200      // 128 f32 (mask, then reused for l-sums)
#define ASMEM  51712

__global__ __launch_bounds__(256) void attn_kernel(
    const u16* __restrict__ Qh, const u16* __restrict__ Kf,
    const u16* __restrict__ Vf, const int* __restrict__ mask,
    u16* __restrict__ attnT) {
  __shared__ __align__(16) unsigned char smem[ASMEM];
  float* AM = (float*)(smem + AOFF_AM);

  int bh = blockIdx.x, b = bh >> 3, h = bh & 7;
  int t0 = blockIdx.y * 128;
  int tid = threadIdx.x;
  int lane = tid & 63, w = tid >> 6;
  int lan15 = lane & 15, quad = lane >> 4;
  int r8 = lane >> 3, c8 = lane & 7;
  int swE = (c8 ^ r8) * 8;

  const u16* Qb = Qh + (size_t)bh * 1024 * 64;
  const u16* Kb = Kf + (size_t)bh * 1152 * 64;
  const u16* Vb = Vf + (size_t)bh * 64 * 1152;
  char* Pw = (char*)smem + AOFF_P + w * 4608;
  u16* Pu = (u16*)Pw;

  if (tid < 128)
    AM[tid] = (tid < SS) ? ((mask[h * SS + tid] != 0) ? 0.f : MASKNEG) : -1e30f;

  // stage Q (wave-private region, overwritten by P later) + chunk 0 K/V
#pragma unroll
  for (int i = 0; i < 4; ++i)
    gl_lds16(Qb + (size_t)(t0 + w * 32 + i * 8 + r8) * 64 + swE, Pw + i * 1024);
#pragma unroll
  for (int i = 0; i < 2; ++i) {
    int row = w * 16 + i * 8;
    gl_lds16(Kb + (size_t)(row + r8) * 64 + swE, (char*)smem + AOFF_K + row * 128);
    gl_lds16(Vb + (size_t)(row + r8) * 1152 + swE, (char*)smem + AOFF_V + row * 128);
  }
  __syncthreads();

  // hoist Q fragments (used as MFMA B-operand: B[k=ch][n=t], t=lan15)
  v8s aq[2][2];
#pragma unroll
  for (int mt = 0; mt < 2; ++mt)
#pragma unroll
    for (int ks = 0; ks < 2; ++ks)
      aq[mt][ks] = *(const v8s*)(Pw + (mt * 16 + lan15) * 128 +
                                 (((ks * 4 + quad) ^ (lan15 & 7)) * 16));

  v4f O[2][4] = {};
  float lsum[2] = {0.f, 0.f};   // per-lane: all 16 chunk values share t=lan15

  for (int c = 0; c < 18; ++c) {
    int cur = c & 1;
    if (c < 17) {
      int nb = cur ^ 1;
#pragma unroll
      for (int i = 0; i < 2; ++i) {
        int row = w * 16 + i * 8;
        gl_lds16(Kb + (size_t)((c + 1) * 64 + row + r8) * 64 + swE,
                 (char*)smem + AOFF_K + nb * 8192 + row * 128);
        gl_lds16(Vb + (size_t)(row + r8) * 1152 + (c + 1) * 64 + swE,
                 (char*)smem + AOFF_V + nb * 8192 + row * 128);
      }
    }
    const char* Kc = (const char*)smem + AOFF_K + cur * 8192;
    const char* Vc = (const char*)smem + AOFF_V + cur * 8192;

    // QK^T transposed: ST[nt][mt], rows = s (quad*4+r), cols = t (lan15)
    v4f ST[4][2] = {};
#pragma unroll
    for (int ks = 0; ks < 2; ++ks) {
      int cofs = ((ks * 4 + quad) ^ (lan15 & 7)) * 16;
      v8s bk[4];
#pragma unroll
      for (int nt = 0; nt < 4; ++nt)
        bk[nt] = *(const v8s*)(Kc + (nt * 16 + lan15) * 128 + cofs);
#pragma unroll
      for (int nt = 0; nt < 4; ++nt)
#pragma unroll
        for (int mt = 0; mt < 2; ++mt)
          ST[nt][mt] = __builtin_amdgcn_mfma_f32_16x16x32_bf16(bk[nt], aq[mt][ks], ST[nt][mt], 0, 0, 0);
    }

    // mask add (enc chunks only): s = c*64 + nt*16 + quad*4 + r
    if (c < 2) {
#pragma unroll
      for (int nt = 0; nt < 4; ++nt)
#pragma unroll
        for (int r = 0; r < 4; ++r) {
          float a_ = AM[c * 64 + nt * 16 + quad * 4 + r];
#pragma unroll
          for (int mt = 0; mt < 2; ++mt) ST[nt][mt][r] += a_;
        }
    }

    // exp2 + b64-packed P store: Pu[(t)*72 + nt*16 + quad*4] = {e0..e3}
#pragma unroll
    for (int mt = 0; mt < 2; ++mt) {
#pragma unroll
      for (int nt = 0; nt < 4; ++nt) {
        float e0 = __builtin_amdgcn_exp2f(ST[nt][mt][0]);
        float e1 = __builtin_amdgcn_exp2f(ST[nt][mt][1]);
        float e2 = __builtin_amdgcn_exp2f(ST[nt][mt][2]);
        float e3 = __builtin_amdgcn_exp2f(ST[nt][mt][3]);
        u16x4 pk; pk.x = hi16(e0); pk.y = hi16(e1); pk.z = hi16(e2); pk.w = hi16(e3);
        *(u16x4*)&Pu[(mt * 16 + lan15) * 72 + nt * 16 + quad * 4] = pk;
        lsum[mt] += (e0 + e1) + (e2 + e3);
      }
    }

    // PV: O[t][c] += P[t][s] V^T[s][c]  (unchanged)
#pragma unroll
    for (int ks = 0; ks < 2; ++ks) {
      int cofs = ((ks * 4 + quad) ^ (lan15 & 7)) * 16;
      v8s ap[2], bv[4];
#pragma unroll
      for (int mt = 0; mt < 2; ++mt)
        ap[mt] = *(const v8s*)(Pw + (mt * 16 + lan15) * 144 + ks * 64 + quad * 16);
#pragma unroll
      for (int nc = 0; nc < 4; ++nc)
        bv[nc] = *(const v8s*)(Vc + (nc * 16 + lan15) * 128 + cofs);
#pragma unroll
      for (int mt = 0; mt < 2; ++mt)
#pragma unroll
        for (int nc = 0; nc < 4; ++nc)
          O[mt][nc] = __builtin_amdgcn_mfma_f32_16x16x32_bf16(ap[mt], bv[nc], O[mt][nc], 0, 0, 0);
    }
    __syncthreads();
  }

  // l: reduce across quads (t=lan15), bounce through LDS to (quad*4+r) index
#pragma unroll
  for (int mt = 0; mt < 2; ++mt) {
    float v = lsum[mt];
    v += __shfl_xor(v, 16, 64);
    v += __shfl_xor(v, 32, 64);
    AM[w * 32 + mt * 16 + lan15] = v;   // 4 quads write identical value
  }
  __syncthreads();
  float inv[2][4];
#pragma unroll
  for (int mt = 0; mt < 2; ++mt)
#pragma unroll
    for (int r = 0; r < 4; ++r)
      inv[mt][r] = 1.0f / AM[w * 32 + mt * 16 + quad * 4 + r];

  float* Ot = (float*)smem;
#pragma unroll
  for (int mt = 0; mt < 2; ++mt)
#pragma unroll
    for (int nc = 0; nc < 4; ++nc)
#pragma unroll
      for (int r = 0; r < 4; ++r)
        Ot[(w * 32 + mt * 16 + quad * 4 + r) * 68 + nc * 16 + lan15] =
            O[mt][nc][r] * inv[mt][r];
  __syncthreads();
  {
    int row = tid >> 1, seg = (tid & 1) * 32;
    const float* src = Ot + row * 68 + seg;
    u16* dp = attnT + ((size_t)b * 1024 + t0 + row) * 512 + h * 64 + seg;
#pragma unroll
    for (int g = 0; g < 4; ++g) {
      u16x8 o;
#pragma unroll
      for (int k = 0; k < 8; ++k) o[k] = f2bf(src[g * 8 + k]);
      *(u16x8*)(dp + g * 8) = o;
    }
  }
}

// ---------------------------------------------------------------------------
extern "C" void kernel_launch(void* const* d_in, const int* in_sizes, int n_in,
                              void* d_out, int out_size, void* d_ws, size_t ws_size,
                              hipStream_t stream) {
  const float* x       = (const float*)d_in[0];
  const float* enc     = (const float*)d_in[1];
  const int*   mask    = (const int*)d_in[2];
  const float* nscale  = (const float*)d_in[3];
  const float* nbias   = (const float*)d_in[4];
  const float* qkv_w   = (const float*)d_in[5];
  const float* qkv_b   = (const float*)d_in[6];
  const float* ekv_w   = (const float*)d_in[7];
  const float* ekv_b   = (const float*)d_in[8];
  const float* proj_w  = (const float*)d_in[9];
  const float* proj_b  = (const float*)d_in[10];
  float* out = (float*)d_out;

  char* ws = (char*)d_ws;
  const size_t MiB = 1048576;
  u16* nrmT   = (u16*)(ws);                        // 8 MiB  [8][1024][512]
  u16* Qh     = (u16*)(ws + 8 * MiB);              // 8 MiB  [64][1024][64]
  u16* Kfull  = (u16*)(ws + 16 * MiB);             // 9.4 MiB [64][1152][64]
  u16* Vfull  = (u16*)(ws + 26 * MiB);             // 9.4 MiB [64][64][1152]
  u16* attnT  = (u16*)(ws + 36 * MiB);             // 8 MiB  [8][1024][512]
  u16* encT   = (u16*)(ws + 44 * MiB);             // 1 MiB  [8][128][512]
  u16* wQK    = (u16*)(ws + 45 * MiB);             // 1 MiB
  u16* wV     = (u16*)(ws + 46 * MiB);             // 0.5 MiB
  u16* wEK    = (u16*)(ws + 46 * MiB + 524288);
  u16* wEV    = (u16*)(ws + 47 * MiB);
  u16* projwb = (u16*)(ws + 47 * MiB + 524288);
  float* bQK  = (float*)(ws + 48 * MiB);
  float* bV   = (float*)(ws + 48 * MiB + 4096);
  float* bEK  = (float*)(ws + 48 * MiB + 6144);
  float* bEV  = (float*)(ws + 48 * MiB + 8192);

  // 1) fused GroupNorm + prep
  prep_gn_kernel<<<dim3(2305), dim3(256), 0, stream>>>(
      x, nscale, nbias, nrmT, qkv_w, ekv_w, proj_w, enc, qkv_b, ekv_b,
      wQK, wV, wEK, wEV, projwb, encT, bQK, bV, bEK, bEV);

  // 2) ALL projections (QK + EK + V + EV) in one launch
  proj_all<<<dim3(104, BB), dim3(256), 0, stream>>>(
      nrmT, encT, wQK, wEK, wV, wEV, bQK, bEK, bV, bEV, Qh, Kfull, Vfull);

  // 3) attention -> attnT [8][1024][512]
  attn_kernel<<<dim3(64, 8), dim3(256), 0, stream>>>(
      Qh, Kfull, Vfull, mask, attnT);

  // 4) out = x + proj_w @ attn
  proj_out<<<dim3(8, 4, BB), dim3(256), 0, stream>>>(
      projwb, attnT, proj_b, x, out);
}